// Round 6
// baseline (377.909 us; speedup 1.0000x reference)
//
#include <hip/hip_runtime.h>
#include <math.h>

// ---------------- problem constants ----------------
// B=2, K=19 -> BK=38 batches; M=1024 points; C=256 feat ch; NPOINT=NSAMPLE=128
#define NBK   38

// ---------------- workspace layout (bytes) ----------------
#define OFF_XC    0u          // [38][3][1024] f32        = 466944
#define OFF_NXYZ  466944u     // [38][128][3]  f32        = 58368
#define OFF_BIDX  525312u     // [38][128][128] i32       = 2490368
#define OFF_W1F   3015680u    // [38][1024][128] f32      = 19922944
#define OFF_PREP  22938624u   // 4096 f32
#define OFF_WT    22955008u   // 32768 f32: c1t (0), c2t (16384)
#define OFF_WF    23086080u   // 131072 shorts: w2/w3 A-frags (0..65535), w1feat A-frags (65536..)
#define OFF_CNT   23348224u   // [38][128] i32 ball counts = 19456

// ---------------- d_out layout (float offsets) ----------------
#define OUT_AGG   24320       // scores at 0: (2,19,128,5)
#define OUT_FEAT  38912       // agg: (2,19,128,3), feat: (2,19,128,128)

typedef short bf16x8 __attribute__((ext_vector_type(8)));   // 8 bf16 = 4 VGPR
typedef float f32x4  __attribute__((ext_vector_type(4)));
typedef int   v4i    __attribute__((ext_vector_type(4)));
typedef int   v2i    __attribute__((ext_vector_type(2)));

// exact IEEE fp32 squared distance, no FMA contraction, ((d0^2+d1^2)+d2^2)
__device__ __forceinline__ float dist2f(float a0, float a1, float a2,
                                        float b0, float b1, float b2) {
#pragma clang fp contract(off)
  float d0 = a0 - b0;
  float d1 = a1 - b1;
  float d2 = a2 - b2;
  return d0 * d0 + d1 * d1 + d2 * d2;
}

// 2-way bf16 split with round-to-nearest-even: v ~= hi + mid, residual <= 2^-18 |v|
__device__ __forceinline__ void split2rn(float v, unsigned& sh, unsigned& sm) {
  unsigned u = __float_as_uint(v);
  unsigned rh = (u + 0x7fffu + ((u >> 16) & 1u)) & 0xffff0000u;
  sh = rh >> 16;
  float r1 = v - __uint_as_float(rh);        // exact in fp32
  unsigned u1 = __float_as_uint(r1);
  unsigned rm = (u1 + 0x7fffu + ((u1 >> 16) & 1u)) & 0xffff0000u;
  sm = rm >> 16;
}

// DPP reduce steps (ALU-speed cross-lane; identity-safe: disabled lanes keep old)
template<int CTRL, int RMASK>
__device__ __forceinline__ float dmax_step(float x) {
  int o = __builtin_amdgcn_update_dpp(__float_as_int(x), __float_as_int(x),
                                      CTRL, RMASK, 0xf, false);
  return fmaxf(x, __int_as_float(o));
}
template<int CTRL, int RMASK>
__device__ __forceinline__ unsigned umin_step(unsigned x) {
  unsigned o = (unsigned)__builtin_amdgcn_update_dpp((int)x, (int)x,
                                                     CTRL, RMASK, 0xf, false);
  return o < x ? o : x;
}

// ---------------- K1: prep (block 64) + weight split (blocks 0..63) ----------------
__global__ __launch_bounds__(256) void prep_wsplit_kernel(
    const float* __restrict__ m1w, const float* __restrict__ m1g, const float* __restrict__ m1be,
    const float* __restrict__ m2w, const float* __restrict__ m2b, const float* __restrict__ m2g, const float* __restrict__ m2be,
    const float* __restrict__ m3w, const float* __restrict__ m3b, const float* __restrict__ m3g, const float* __restrict__ m3be,
    const float* __restrict__ c1w, const float* __restrict__ c1b, const float* __restrict__ c1g, const float* __restrict__ c1be,
    const float* __restrict__ c2w, const float* __restrict__ c2b, const float* __restrict__ c2g, const float* __restrict__ c2be,
    float* __restrict__ prep, short* __restrict__ Wf, float* __restrict__ wt)
{
  int t = threadIdx.x;
  if (blockIdx.x == 64) {
    if (t < 128) {
      float inv = 1.0f / sqrtf(1.0f + 1e-5f);
      float a1 = m1g[t] * inv;
      prep[t] = a1;
      float a2 = m2g[t] * inv;  prep[256 + t] = a2;  prep[384 + t] = fmaf(m2b[t], a2, m2be[t]);
      float a3 = m3g[t] * inv;  prep[512 + t] = a3;  prep[640 + t] = fmaf(m3b[t], a3, m3be[t]);
      float ac1 = c1g[t] * inv; prep[768 + t] = ac1; prep[896 + t] = fmaf(c1b[t], ac1, c1be[t]);
      float ac2 = c2g[t] * inv; prep[1024 + t] = ac2; prep[1152 + t] = fmaf(c2b[t], ac2, c2be[t]);
      prep[1280 + 4 * t + 0] = m1w[t * 259 + 0] * a1;
      prep[1280 + 4 * t + 1] = m1w[t * 259 + 1] * a1;
      prep[1280 + 4 * t + 2] = m1w[t * 259 + 2] * a1;
      prep[1280 + 4 * t + 3] = m1be[t];
    }
    return;
  }
  int idx = blockIdx.x * 256 + t;                // 0..16383
#pragma unroll
  for (int e = 0; e < 4; ++e) {
    int i = idx * 4 + e;                         // 0..65535
    if (i < 32768) {
      int c = i & 127, o = (i >> 7) & 127, l = i >> 14;
      float w = (l ? m3w : m2w)[o * 128 + c];
      unsigned sh, sm;
      split2rn(w, sh, sm);
      int ot = o >> 4, mm = o & 15, kk = c >> 5, q = (c & 31) >> 3, j = c & 7;
      int within = (q * 16 + mm) * 8 + j;
      Wf[(((l * 2 + 0) * 4 + kk) * 8 + ot) * 512 + within] = (short)sh;
      Wf[(((l * 2 + 1) * 4 + kk) * 8 + ot) * 512 + within] = (short)sm;
    } else {
      int jdx = i - 32768;
      int o = jdx >> 8, c = jdx & 255;
      float w = m1w[o * 259 + 3 + c];
      unsigned sh, sm;
      split2rn(w, sh, sm);
      int ot = o >> 4, mm = o & 15, kk = c >> 5, q = (c & 31) >> 3, j = c & 7;
      int within = (q * 16 + mm) * 8 + j;
      Wf[65536 + ((kk) * 8 + ot) * 512 + within] = (short)sh;
      Wf[65536 + ((8 + kk) * 8 + ot) * 512 + within] = (short)sm;
    }
  }
  {
    int c = idx >> 7, o = idx & 127;
    wt[idx] = c1w[o * 128 + c];                   // c1t[c][o]
    wt[16384 + idx] = c2w[o * 128 + c];           // c2t[c][o]
  }
}

// ---------------- K2: fps+ball (blocks 0..37) || w1f (blocks 38..) ----------------
// fps: wave0 runs the serial 128-iter FPS with DPP reductions (no barriers in loop);
// then all 4 waves run the ball query from LDS-resident points/centers.
__global__ __launch_bounds__(256, 2) void fused_k2_kernel(
    const float* __restrict__ xyz, const float* __restrict__ feats,
    const float* __restrict__ m1b, const float* __restrict__ prep,
    const short* __restrict__ Wf,
    float* __restrict__ xc, float* __restrict__ nxyz, float* __restrict__ agg,
    int* __restrict__ bidx, int* __restrict__ counts, float* __restrict__ W1f)
{
  __shared__ __align__(16) char smem[32768];
  int t = threadIdx.x;
  int wave = t >> 6, lane = t & 63;

  if (blockIdx.x < NBK) {
    // ================= FPS + ball =================
    int bk = blockIdx.x;
    int b = bk / 19, k = bk % 19;
    float* sx0 = (float*)smem;            // 1024
    float* sx1 = sx0 + 1024;
    float* sx2 = sx1 + 1024;
    float* scen = sx2 + 1024;             // 384
    // load all points (4 waves), write xc
#pragma unroll
    for (int j = 0; j < 4; ++j) {
      int i = j * 256 + t;
      const float* src = xyz + ((size_t)((b * 1024 + i) * 19 + k)) * 3;
      float v0 = src[0], v1 = src[1], v2 = src[2];
      sx0[i] = v0; sx1[i] = v1; sx2[i] = v2;
      xc[(bk * 3 + 0) * 1024 + i] = v0;
      xc[(bk * 3 + 1) * 1024 + i] = v1;
      xc[(bk * 3 + 2) * 1024 + i] = v2;
    }
    __syncthreads();

    if (wave == 0) {
      float px[16], py[16], pz[16], dist[16];
#pragma unroll
      for (int j = 0; j < 16; ++j) {
        int i = j * 64 + lane;
        px[j] = sx0[i]; py[j] = sx1[i]; pz[j] = sx2[i];
        dist[j] = 1e10f;
      }
      int istar = 0;
      for (int it = 0; it < 128; ++it) {
        float c0 = sx0[istar], c1 = sx1[istar], c2 = sx2[istar];  // broadcast reads
        if (lane < 3) {
          float cv = (lane == 0) ? c0 : ((lane == 1) ? c1 : c2);
          nxyz[(bk * 128 + it) * 3 + lane] = cv;
          agg[(bk * 128 + it) * 3 + lane]  = cv;
          scen[it * 3 + lane] = cv;
        }
        float dbest = -1.f; int jbest = 0;
#pragma unroll
        for (int j = 0; j < 16; ++j) {
          float d = dist2f(px[j], py[j], pz[j], c0, c1, c2);
          float dj = fminf(dist[j], d);
          dist[j] = dj;
          if (dj > dbest) { dbest = dj; jbest = j; }   // first-max within lane
        }
        // wave max via DPP (lane 63 ends with the full max)
        float x = dbest;
        x = dmax_step<0x111, 0xf>(x);
        x = dmax_step<0x112, 0xf>(x);
        x = dmax_step<0x114, 0xf>(x);
        x = dmax_step<0x118, 0xf>(x);
        x = dmax_step<0x142, 0xa>(x);
        x = dmax_step<0x143, 0xc>(x);
        float dmax = __int_as_float(__builtin_amdgcn_readlane(__float_as_int(x), 63));
        // exact first-max index: min flat index among achieving lanes (i = j*64+lane)
        unsigned cand = (dbest == dmax) ? (unsigned)((jbest << 6) | lane) : 0xffffu;
        cand = umin_step<0x111, 0xf>(cand);
        cand = umin_step<0x112, 0xf>(cand);
        cand = umin_step<0x114, 0xf>(cand);
        cand = umin_step<0x118, 0xf>(cand);
        cand = umin_step<0x142, 0xa>(cand);
        cand = umin_step<0x143, 0xc>(cand);
        istar = (int)((unsigned)__builtin_amdgcn_readlane((int)cand, 63) & 0xffffu);
      }
    }
    __syncthreads();

    // ---- ball query: each wave handles 32 balls from LDS ----
    for (int p = wave * 32; p < wave * 32 + 32; ++p) {
      float c0 = scen[p * 3 + 0], c1 = scen[p * 3 + 1], c2 = scen[p * 3 + 2];
      int* outp = bidx + ((size_t)(bk * 128 + p)) * 128;
      int count = 0, first = 0;
      bool got = false;
      for (int ch = 0; ch < 16 && count < 128; ++ch) {
        int m = (ch << 6) + lane;
        float d = dist2f(sx0[m], sx1[m], sx2[m], c0, c1, c2);
        bool flag = d < 0.0225f;                 // strict fp32, RADIUS^2
        unsigned long long mask = __ballot(flag);
        if (!got && mask) { first = (ch << 6) + __builtin_ctzll(mask); got = true; }
        int pos = count + (int)__popcll(mask & ((1ull << lane) - 1ull));
        if (flag && pos < 128) outp[pos] = m;
        count += (int)__popcll(mask);
      }
      for (int j = count + lane; j < 128; j += 64) outp[j] = first;
      if (lane == 0) counts[bk * 128 + p] = count > 128 ? 128 : count;
    }
    return;
  }

  // ================= w1f =================
  short* ffrag = (short*)smem;                    // 32KB: [sp2][kkl2][st8]*512
  int blk = blockIdx.x - NBK;
  int bk = blk >> 3, m0 = (blk & 7) << 7;
  int b = bk / 19, k = bk % 19;
  int quad = lane >> 4, nl = lane & 15;
  int mloc = t & 127, chalf = t >> 7;
  int st_w = mloc >> 4, sl_w = mloc & 15;
  const float* fbase = feats + ((size_t)(b * 4864 + k)) * 1024 + m0 + mloc;
  const short* WA = Wf + 65536;

  f32x4 acc[2][8];
#pragma unroll
  for (int oi = 0; oi < 2; ++oi)
#pragma unroll
    for (int st = 0; st < 8; ++st) acc[oi][st] = (f32x4){0.f, 0.f, 0.f, 0.f};

  for (int ch = 0; ch < 4; ++ch) {
    int cbase = ch * 64 + chalf * 32;
#pragma unroll
    for (int g = 0; g < 4; ++g) {
      float v[8];
#pragma unroll
      for (int j = 0; j < 8; ++j)
        v[j] = fbase[(size_t)(cbase + g * 8 + j) * 19456];
      unsigned sh[8], sm[8];
#pragma unroll
      for (int j = 0; j < 8; ++j) split2rn(v[j], sh[j], sm[j]);
      int base = chalf * 4096 + st_w * 512 + (g * 16 + sl_w) * 8;
      v4i ph = {(int)(sh[0] | (sh[1] << 16)), (int)(sh[2] | (sh[3] << 16)),
                (int)(sh[4] | (sh[5] << 16)), (int)(sh[6] | (sh[7] << 16))};
      *(v4i*)&ffrag[base] = ph;
      v4i pm = {(int)(sm[0] | (sm[1] << 16)), (int)(sm[2] | (sm[3] << 16)),
                (int)(sm[4] | (sm[5] << 16)), (int)(sm[6] | (sm[7] << 16))};
      *(v4i*)&ffrag[base + 8192] = pm;
    }
    __syncthreads();
#pragma unroll
    for (int kkl = 0; kkl < 2; ++kkl) {
      int kk = ch * 2 + kkl;
      bf16x8 a[2][2];
#pragma unroll
      for (int oi = 0; oi < 2; ++oi)
#pragma unroll
        for (int sp = 0; sp < 2; ++sp)
          a[oi][sp] = *(const bf16x8*)(WA + ((sp * 8 + kk) * 8 + wave * 2 + oi) * 512 + lane * 8);
#pragma unroll
      for (int st = 0; st < 8; ++st) {
        const short* hb = ffrag + kkl * 4096 + st * 512 + lane * 8;
        bf16x8 b0 = *(const bf16x8*)hb;
        bf16x8 b1 = *(const bf16x8*)(hb + 8192);
#pragma unroll
        for (int oi = 0; oi < 2; ++oi) {
          f32x4 c = acc[oi][st];
          c = __builtin_amdgcn_mfma_f32_16x16x32_bf16(a[oi][1], b0, c, 0, 0, 0);
          c = __builtin_amdgcn_mfma_f32_16x16x32_bf16(a[oi][0], b1, c, 0, 0, 0);
          c = __builtin_amdgcn_mfma_f32_16x16x32_bf16(a[oi][0], b0, c, 0, 0, 0);
          acc[oi][st] = c;
        }
      }
    }
    __syncthreads();
  }
#pragma unroll
  for (int oi = 0; oi < 2; ++oi) {
    int o0 = (wave * 2 + oi) * 16 + quad * 4;
    float4 bb = *(const float4*)&m1b[o0];
    float4 al = *(const float4*)&prep[o0];
#pragma unroll
    for (int st = 0; st < 8; ++st) {
      int m_out = m0 + st * 16 + nl;
      f32x4 cc = acc[oi][st];
      float4 r;
      r.x = (cc[0] + bb.x) * al.x;
      r.y = (cc[1] + bb.y) * al.y;
      r.z = (cc[2] + bb.z) * al.z;
      r.w = (cc[3] + bb.w) * al.w;
      *(float4*)&W1f[((size_t)(bk * 1024 + m_out)) * 128 + o0] = r;
    }
  }
}

// ---------------- MFMA GEMM over one 128(c) x nst_h*16(s) fragment buffer ----------
__device__ __forceinline__ void mfma_layer(const short* __restrict__ Wf,
                                           const short* hfrag, int l,
                                           int wave, int lane, int nst_h,
                                           f32x4 acc[2][4])
{
#pragma unroll 1
  for (int kk = 0; kk < 4; ++kk) {
    bf16x8 a[2][2];
#pragma unroll
    for (int oi = 0; oi < 2; ++oi)
#pragma unroll
      for (int sp = 0; sp < 2; ++sp)
        a[oi][sp] = *(const bf16x8*)(Wf + (((l * 2 + sp) * 4 + kk) * 8 + (wave * 2 + oi)) * 512 + lane * 8);
    for (int st = 0; st < nst_h; ++st) {
      const short* hb = hfrag + kk * 2048 + st * 512 + lane * 8;
      bf16x8 b0 = *(const bf16x8*)(hb);           // hi
      bf16x8 b1 = *(const bf16x8*)(hb + 8192);    // mid
#pragma unroll
      for (int oi = 0; oi < 2; ++oi) {
        f32x4 c = acc[oi][st];
        c = __builtin_amdgcn_mfma_f32_16x16x32_bf16(a[oi][1], b0, c, 0, 0, 0);
        c = __builtin_amdgcn_mfma_f32_16x16x32_bf16(a[oi][0], b1, c, 0, 0, 0);
        c = __builtin_amdgcn_mfma_f32_16x16x32_bf16(a[oi][0], b0, c, 0, 0, 0);
        acc[oi][st] = c;
      }
    }
  }
}

// ---------------- fused SA: 4 balls per block, tiles packed over passes ----------
__global__ __launch_bounds__(256, 3) void sa_kernel(
    const float* __restrict__ xc, const float* __restrict__ nxyz,
    const int* __restrict__ bidx, const int* __restrict__ counts,
    const float* __restrict__ W1f, const float* __restrict__ prep,
    const short* __restrict__ Wf, float* __restrict__ feat_out)
{
  __shared__ __align__(16) short hfrag[16384];   // 32KB
  __shared__ float pcs[512];
  __shared__ float sm[32 * 128];                 // 16KB per-tile o-max
  __shared__ float ccen[12];
  __shared__ int scnt[4];
  int gb = blockIdx.x, bk = gb >> 5, pb = (gb & 31) << 2;
  int t = threadIdx.x;
  int wave = t >> 6, lane = t & 63;
  int quad = lane >> 4, nl = lane & 15;

  pcs[t] = prep[1280 + t];
  pcs[256 + t] = prep[1536 + t];
  if (t < 4) scnt[t] = counts[bk * 128 + pb + t];
  if (t < 12) {
    int bb = t / 3, c = t % 3;
    ccen[t] = nxyz[(bk * 128 + pb + bb) * 3 + c];
  }
  __syncthreads();
  int n0 = (scnt[0] + 15) >> 4, n1 = (scnt[1] + 15) >> 4;
  int n2 = (scnt[2] + 15) >> 4, n3 = (scnt[3] + 15) >> 4;
  int pf1 = n0, pf2 = n0 + n1, pf3 = n0 + n1 + n2, T = n0 + n1 + n2 + n3;

  for (int q0 = 0; q0 < T; q0 += 4) {
    int nst_h = T - q0;
    if (nst_h > 4) nst_h = 4;
    // ---- h1 build ----
    {
      int cg = wave;
      int st = lane >> 4, sl = lane & 15;
      if (st < nst_h) {
        int q = q0 + st;
        int bq = (q >= pf1) + (q >= pf2) + (q >= pf3);
        int tstart = (bq == 0) ? 0 : (bq == 1) ? pf1 : (bq == 2) ? pf2 : pf3;
        int tslot = q - tstart;
        int m = bidx[((size_t)(bk * 128 + pb + bq)) * 128 + tslot * 16 + sl];
        float cen0 = ccen[bq * 3 + 0], cen1 = ccen[bq * 3 + 1], cen2 = ccen[bq * 3 + 2];
        float g0 = (xc[(bk * 3 + 0) * 1024 + m] - cen0) * (1.0f / 0.15f);
        float g1 = (xc[(bk * 3 + 1) * 1024 + m] - cen1) * (1.0f / 0.15f);
        float g2 = (xc[(bk * 3 + 2) * 1024 + m] - cen2) * (1.0f / 0.15f);
        const float4* wrow = (const float4*)(W1f + ((size_t)(bk * 1024 + m)) * 128 + cg * 32);
        const float4* pcp = (const float4*)pcs + cg * 32;
#pragma unroll
        for (int g = 0; g < 4; ++g) {
          float4 wva = wrow[g * 2], wvb = wrow[g * 2 + 1];
          float wv[8] = {wva.x, wva.y, wva.z, wva.w, wvb.x, wvb.y, wvb.z, wvb.w};
          unsigned sh[8], smv[8];
#pragma unroll
          for (int e = 0; e < 8; ++e) {
            float4 pc = pcp[g * 8 + e];
            float hv = fmaxf(wv[e] + pc.x * g0 + pc.y * g1 + pc.z * g2 + pc.w, 0.f);
            split2rn(hv, sh[e], smv[e]);
          }
          int base = (cg * 4 + st) * 512 + (g * 16 + sl) * 8;
          v4i ph = {(int)(sh[0] | (sh[1] << 16)), (int)(sh[2] | (sh[3] << 16)),
                    (int)(sh[4] | (sh[5] << 16)), (int)(sh[6] | (sh[7] << 16))};
          *(v4i*)&hfrag[base] = ph;
          v4i pm = {(int)(smv[0] | (smv[1] << 16)), (int)(smv[2] | (smv[3] << 16)),
                    (int)(smv[4] | (smv[5] << 16)), (int)(smv[6] | (smv[7] << 16))};
          *(v4i*)&hfrag[base + 8192] = pm;
        }
      }
    }
    __syncthreads();

    // ---- layer 2 ----
    f32x4 acc[2][4];
#pragma unroll
    for (int oi = 0; oi < 2; ++oi)
#pragma unroll
      for (int st = 0; st < 4; ++st) acc[oi][st] = (f32x4){0.f, 0.f, 0.f, 0.f};
    mfma_layer(Wf, hfrag, 0, wave, lane, nst_h, acc);
    __syncthreads();

    // ---- h2 epilogue ----
#pragma unroll
    for (int oi = 0; oi < 2; ++oi) {
      int o0 = (wave * 2 + oi) * 16 + quad * 4;
      float4 al = *(const float4*)&prep[256 + o0];
      float4 be = *(const float4*)&prep[384 + o0];
      int kk2 = o0 >> 5, g2 = (o0 & 31) >> 3, j0 = o0 & 7;
      for (int st = 0; st < nst_h; ++st) {
        f32x4 cc = acc[oi][st];
        float v0 = fmaxf(fmaf(cc[0], al.x, be.x), 0.f);
        float v1 = fmaxf(fmaf(cc[1], al.y, be.y), 0.f);
        float v2 = fmaxf(fmaf(cc[2], al.z, be.z), 0.f);
        float v3 = fmaxf(fmaf(cc[3], al.w, be.w), 0.f);
        unsigned h0, m0_, h1, m1_, h2, m2_, h3, m3_;
        split2rn(v0, h0, m0_); split2rn(v1, h1, m1_);
        split2rn(v2, h2, m2_); split2rn(v3, h3, m3_);
        int base = (kk2 * 4 + st) * 512 + (g2 * 16 + nl) * 8 + j0;
        v2i w0 = {(int)(h0 | (h1 << 16)), (int)(h2 | (h3 << 16))};
        *(v2i*)&hfrag[base] = w0;
        v2i w1 = {(int)(m0_ | (m1_ << 16)), (int)(m2_ | (m3_ << 16))};
        *(v2i*)&hfrag[base + 8192] = w1;
      }
    }
    __syncthreads();

    // ---- layer 3 ----
#pragma unroll
    for (int oi = 0; oi < 2; ++oi)
#pragma unroll
      for (int st = 0; st < 4; ++st) acc[oi][st] = (f32x4){0.f, 0.f, 0.f, 0.f};
    mfma_layer(Wf, hfrag, 1, wave, lane, nst_h, acc);

    // ---- layer-3 epilogue: BN+ReLU, quad-reduce max per tile ----
#pragma unroll
    for (int oi = 0; oi < 2; ++oi) {
      int o0 = (wave * 2 + oi) * 16 + quad * 4;
      float4 al = *(const float4*)&prep[512 + o0];
      float4 be = *(const float4*)&prep[640 + o0];
      for (int st = 0; st < nst_h; ++st) {
        f32x4 cc = acc[oi][st];
        float v[4];
        v[0] = fmaxf(fmaf(cc[0], al.x, be.x), 0.f);
        v[1] = fmaxf(fmaf(cc[1], al.y, be.y), 0.f);
        v[2] = fmaxf(fmaf(cc[2], al.z, be.z), 0.f);
        v[3] = fmaxf(fmaf(cc[3], al.w, be.w), 0.f);
#pragma unroll
        for (int r = 0; r < 4; ++r) {
          float x = v[r];
          x = fmaxf(x, __shfl_xor(x, 1));
          x = fmaxf(x, __shfl_xor(x, 2));
          x = fmaxf(x, __shfl_xor(x, 4));
          x = fmaxf(x, __shfl_xor(x, 8));
          if (nl == 0) sm[(q0 + st) * 128 + o0 + r] = x;
        }
      }
    }
    __syncthreads();
  }

  // ---- final: merge tiles per ball, write feat ----
#pragma unroll
  for (int e = t; e < 512; e += 256) {
    int bb = e >> 7, o = e & 127;
    int qs = (bb == 0) ? 0 : (bb == 1) ? pf1 : (bb == 2) ? pf2 : pf3;
    int nq = (bb == 0) ? n0 : (bb == 1) ? n1 : (bb == 2) ? n2 : n3;
    float v = sm[qs * 128 + o];
    for (int q = 1; q < nq; ++q) v = fmaxf(v, sm[(qs + q) * 128 + o]);
    feat_out[(((size_t)bk) << 14) + (o << 7) + pb + bb] = v;
  }
}

// 8x8 register-tile GEMM over a 128x128 LDS operand; w is [c][o] in global
__device__ __forceinline__ void gemm_tile(const float* __restrict__ w,
                                          const float* lds, int tx, int ty,
                                          float acc[8][8])
{
#pragma unroll
  for (int i = 0; i < 8; ++i)
#pragma unroll
    for (int j = 0; j < 8; ++j) acc[i][j] = 0.f;
  for (int c = 0; c < 128; ++c) {
    const float4* wr = (const float4*)(w + c * 128 + ty * 8);
    float4 a0 = wr[0], a1 = wr[1];
    const float4* hr = (const float4*)(lds + c * 128 + tx * 8);
    float4 b0 = hr[0], b1 = hr[1];
    float av[8] = {a0.x, a0.y, a0.z, a0.w, a1.x, a1.y, a1.z, a1.w};
    float bv[8] = {b0.x, b0.y, b0.z, b0.w, b1.x, b1.y, b1.z, b1.w};
#pragma unroll
    for (int i = 0; i < 8; ++i)
#pragma unroll
      for (int j = 0; j < 8; ++j) acc[i][j] = fmaf(av[i], bv[j], acc[i][j]);
  }
}

// ---------------- head: c1 -> c2 -> op -> scores ----------------
__global__ __launch_bounds__(256) void head_kernel(const float* __restrict__ featg,
    const float* __restrict__ prep, const float* __restrict__ wt,
    const float* __restrict__ nxyz, const float* __restrict__ opw,
    const float* __restrict__ opb, float* __restrict__ scores)
{
  __shared__ __align__(16) float buf[128 * 128];
  int bk = blockIdx.x, t = threadIdx.x;
  for (int i = t; i < 16384; i += 256) buf[i] = featg[(bk << 14) + i];
  __syncthreads();
  int tx = t & 15, ty = t >> 4;
  float acc[8][8];

  // c1
  gemm_tile(wt, buf, tx, ty, acc);
  __syncthreads();
#pragma unroll
  for (int i = 0; i < 8; ++i) {
    int o = ty * 8 + i;
    float al = prep[768 + o], be = prep[896 + o];
#pragma unroll
    for (int j = 0; j < 8; ++j)
      buf[o * 128 + tx * 8 + j] = fmaxf(fmaf(acc[i][j], al, be), 0.f);
  }
  __syncthreads();

  // c2
  gemm_tile(wt + 16384, buf, tx, ty, acc);
  __syncthreads();
#pragma unroll
  for (int i = 0; i < 8; ++i) {
    int o = ty * 8 + i;
    float al = prep[1024 + o], be = prep[1152 + o];
#pragma unroll
    for (int j = 0; j < 8; ++j)
      buf[o * 128 + tx * 8 + j] = fmaxf(fmaf(acc[i][j], al, be), 0.f);
  }
  __syncthreads();

  // op head + scores assembly
  if (t < 128) {
    int p = t, k = bk % 19;
    float res[5];
#pragma unroll
    for (int j = 0; j < 5; ++j) {
      const float* wr = opw + ((size_t)(k * 5 + j)) * 128;
      float a = opb[k * 5 + j];
      for (int c = 0; c < 128; ++c) a = fmaf(wr[c], buf[c * 128 + p], a);
      res[j] = a;
    }
    float a0 = nxyz[(bk * 128 + p) * 3 + 0];
    float a1 = nxyz[(bk * 128 + p) * 3 + 1];
    float a2 = nxyz[(bk * 128 + p) * 3 + 2];
    float* sc = scores + ((size_t)(bk * 128 + p)) * 5;
    sc[0] = res[0];
    sc[1] = res[1];
    sc[2] = a0 + res[2];
    sc[3] = a1 + res[3];
    sc[4] = a2 + res[4];
  }
}

extern "C" void kernel_launch(void* const* d_in, const int* in_sizes, int n_in,
                              void* d_out, int out_size, void* d_ws, size_t ws_size,
                              hipStream_t stream) {
  (void)in_sizes; (void)n_in; (void)out_size; (void)ws_size;
  const float* xyz  = (const float*)d_in[0];
  const float* fts  = (const float*)d_in[1];
  const float* m1w  = (const float*)d_in[2];
  const float* m1b  = (const float*)d_in[3];
  const float* m1g  = (const float*)d_in[4];
  const float* m1be = (const float*)d_in[5];
  const float* m2w  = (const float*)d_in[6];
  const float* m2b  = (const float*)d_in[7];
  const float* m2g  = (const float*)d_in[8];
  const float* m2be = (const float*)d_in[9];
  const float* m3w  = (const float*)d_in[10];
  const float* m3b  = (const float*)d_in[11];
  const float* m3g  = (const float*)d_in[12];
  const float* m3be = (const float*)d_in[13];
  const float* c1w  = (const float*)d_in[14];
  const float* c1b  = (const float*)d_in[15];
  const float* c1g  = (const float*)d_in[16];
  const float* c1be = (const float*)d_in[17];
  const float* c2w  = (const float*)d_in[18];
  const float* c2b  = (const float*)d_in[19];
  const float* c2g  = (const float*)d_in[20];
  const float* c2be = (const float*)d_in[21];
  const float* opw  = (const float*)d_in[22];
  const float* opb  = (const float*)d_in[23];

  float* out = (float*)d_out;
  char* ws = (char*)d_ws;
  float* xc   = (float*)(ws + OFF_XC);
  float* nxyz = (float*)(ws + OFF_NXYZ);
  int*   bidx = (int*)(ws + OFF_BIDX);
  float* W1f  = (float*)(ws + OFF_W1F);
  float* prep = (float*)(ws + OFF_PREP);
  float* wt   = (float*)(ws + OFF_WT);
  short* Wf   = (short*)(ws + OFF_WF);
  int*   cnt  = (int*)(ws + OFF_CNT);

  hipLaunchKernelGGL(prep_wsplit_kernel, dim3(65), dim3(256), 0, stream,
                     m1w, m1g, m1be, m2w, m2b, m2g, m2be, m3w, m3b, m3g, m3be,
                     c1w, c1b, c1g, c1be, c2w, c2b, c2g, c2be, prep, Wf, wt);
  hipLaunchKernelGGL(fused_k2_kernel, dim3(NBK + NBK * 8), dim3(256), 0, stream,
                     xyz, fts, m1b, prep, Wf,
                     xc, nxyz, out + OUT_AGG, bidx, cnt, W1f);
  hipLaunchKernelGGL(sa_kernel, dim3(NBK * 32), dim3(256), 0, stream,
                     xc, nxyz, bidx, cnt, W1f, prep, Wf, out + OUT_FEAT);
  hipLaunchKernelGGL(head_kernel, dim3(NBK), dim3(256), 0, stream,
                     out + OUT_FEAT, prep, wt, nxyz, opw, opb, out);
}

// Round 7
// 362.568 us; speedup vs baseline: 1.0423x; 1.0423x over previous
//
#include <hip/hip_runtime.h>
#include <math.h>

// ---------------- problem constants ----------------
// B=2, K=19 -> BK=38 batches; M=1024 points; C=256 feat ch; NPOINT=NSAMPLE=128
#define NBK   38

// ---------------- workspace layout (bytes) ----------------
#define OFF_XC    0u          // [38][3][1024] f32        = 466944
#define OFF_NXYZ  466944u     // [38][128][3]  f32        = 58368
#define OFF_BIDX  525312u     // [38][128][128] i32       = 2490368
#define OFF_W1F   3015680u    // [38][1024][128] f32      = 19922944
#define OFF_PREP  22938624u   // 4096 f32
#define OFF_WF    22955008u   // 196608 shorts: w2/w3 (0), w1feat (65536), c1/c2 (131072)
#define OFF_CNT   23348224u   // [38][128] i32 ball counts = 19456

// ---------------- d_out layout (float offsets) ----------------
#define OUT_AGG   24320       // scores at 0: (2,19,128,5)
#define OUT_FEAT  38912       // agg: (2,19,128,3), feat: (2,19,128,128)

typedef short bf16x8 __attribute__((ext_vector_type(8)));   // 8 bf16 = 4 VGPR
typedef float f32x4  __attribute__((ext_vector_type(4)));
typedef int   v4i    __attribute__((ext_vector_type(4)));
typedef int   v2i    __attribute__((ext_vector_type(2)));

// exact IEEE fp32 squared distance, no FMA contraction, ((d0^2+d1^2)+d2^2)
__device__ __forceinline__ float dist2f(float a0, float a1, float a2,
                                        float b0, float b1, float b2) {
#pragma clang fp contract(off)
  float d0 = a0 - b0;
  float d1 = a1 - b1;
  float d2 = a2 - b2;
  return d0 * d0 + d1 * d1 + d2 * d2;
}

// 2-way bf16 split with round-to-nearest-even: v ~= hi + mid, residual <= 2^-18 |v|
__device__ __forceinline__ void split2rn(float v, unsigned& sh, unsigned& sm) {
  unsigned u = __float_as_uint(v);
  unsigned rh = (u + 0x7fffu + ((u >> 16) & 1u)) & 0xffff0000u;
  sh = rh >> 16;
  float r1 = v - __uint_as_float(rh);        // exact in fp32
  unsigned u1 = __float_as_uint(r1);
  unsigned rm = (u1 + 0x7fffu + ((u1 >> 16) & 1u)) & 0xffff0000u;
  sm = rm >> 16;
}

// DPP reduce steps (ALU-speed cross-lane; lane 63 ends with the full reduction)
template<int CTRL, int RMASK>
__device__ __forceinline__ float fmax_dpp(float x) {
  int o = __builtin_amdgcn_update_dpp(__float_as_int(x), __float_as_int(x),
                                      CTRL, RMASK, 0xf, false);
  return fmaxf(x, __int_as_float(o));
}
template<int CTRL, int RMASK>
__device__ __forceinline__ unsigned umax_dpp(unsigned x) {
  unsigned o = (unsigned)__builtin_amdgcn_update_dpp((int)x, (int)x,
                                                     CTRL, RMASK, 0xf, false);
  return o > x ? o : x;
}
__device__ __forceinline__ float wave_fmax(float x) {
  x = fmax_dpp<0x111, 0xf>(x);
  x = fmax_dpp<0x112, 0xf>(x);
  x = fmax_dpp<0x114, 0xf>(x);
  x = fmax_dpp<0x118, 0xf>(x);
  x = fmax_dpp<0x142, 0xa>(x);
  x = fmax_dpp<0x143, 0xc>(x);
  return __int_as_float(__builtin_amdgcn_readlane(__float_as_int(x), 63));
}
__device__ __forceinline__ unsigned wave_umax(unsigned x) {
  x = umax_dpp<0x111, 0xf>(x);
  x = umax_dpp<0x112, 0xf>(x);
  x = umax_dpp<0x114, 0xf>(x);
  x = umax_dpp<0x118, 0xf>(x);
  x = umax_dpp<0x142, 0xa>(x);
  x = umax_dpp<0x143, 0xc>(x);
  return (unsigned)__builtin_amdgcn_readlane((int)x, 63);
}

// ---------------- K1: weight split (0..63: w2/w3/w1f, 64..95: c1/c2), prep (96) ----
__global__ __launch_bounds__(256) void prep_wsplit_kernel(
    const float* __restrict__ m1w, const float* __restrict__ m1g, const float* __restrict__ m1be,
    const float* __restrict__ m2w, const float* __restrict__ m2b, const float* __restrict__ m2g, const float* __restrict__ m2be,
    const float* __restrict__ m3w, const float* __restrict__ m3b, const float* __restrict__ m3g, const float* __restrict__ m3be,
    const float* __restrict__ c1w, const float* __restrict__ c1b, const float* __restrict__ c1g, const float* __restrict__ c1be,
    const float* __restrict__ c2w, const float* __restrict__ c2b, const float* __restrict__ c2g, const float* __restrict__ c2be,
    float* __restrict__ prep, short* __restrict__ Wf)
{
  int t = threadIdx.x;
  if (blockIdx.x == 96) {
    if (t < 128) {
      float inv = 1.0f / sqrtf(1.0f + 1e-5f);
      float a1 = m1g[t] * inv;
      prep[t] = a1;
      float a2 = m2g[t] * inv;  prep[256 + t] = a2;  prep[384 + t] = fmaf(m2b[t], a2, m2be[t]);
      float a3 = m3g[t] * inv;  prep[512 + t] = a3;  prep[640 + t] = fmaf(m3b[t], a3, m3be[t]);
      float ac1 = c1g[t] * inv; prep[768 + t] = ac1; prep[896 + t] = fmaf(c1b[t], ac1, c1be[t]);
      float ac2 = c2g[t] * inv; prep[1024 + t] = ac2; prep[1152 + t] = fmaf(c2b[t], ac2, c2be[t]);
      prep[1280 + 4 * t + 0] = m1w[t * 259 + 0] * a1;
      prep[1280 + 4 * t + 1] = m1w[t * 259 + 1] * a1;
      prep[1280 + 4 * t + 2] = m1w[t * 259 + 2] * a1;
      prep[1280 + 4 * t + 3] = m1be[t];
    }
    return;
  }
  if (blockIdx.x >= 64) {
    // c1/c2 A-frags at Wf+131072
    int idx2 = (blockIdx.x - 64) * 256 + t;        // 0..8191
#pragma unroll
    for (int e = 0; e < 4; ++e) {
      int i = idx2 * 4 + e;                        // 0..32767
      int c = i & 127, o = (i >> 7) & 127, l = i >> 14;
      float w = (l ? c2w : c1w)[o * 128 + c];
      unsigned sh, sm;
      split2rn(w, sh, sm);
      int ot = o >> 4, mm = o & 15, kk = c >> 5, q = (c & 31) >> 3, j = c & 7;
      int within = (q * 16 + mm) * 8 + j;
      Wf[131072 + (((l * 2 + 0) * 4 + kk) * 8 + ot) * 512 + within] = (short)sh;
      Wf[131072 + (((l * 2 + 1) * 4 + kk) * 8 + ot) * 512 + within] = (short)sm;
    }
    return;
  }
  int idx = blockIdx.x * 256 + t;                  // 0..16383
#pragma unroll
  for (int e = 0; e < 4; ++e) {
    int i = idx * 4 + e;                           // 0..65535
    if (i < 32768) {
      int c = i & 127, o = (i >> 7) & 127, l = i >> 14;
      float w = (l ? m3w : m2w)[o * 128 + c];
      unsigned sh, sm;
      split2rn(w, sh, sm);
      int ot = o >> 4, mm = o & 15, kk = c >> 5, q = (c & 31) >> 3, j = c & 7;
      int within = (q * 16 + mm) * 8 + j;
      Wf[(((l * 2 + 0) * 4 + kk) * 8 + ot) * 512 + within] = (short)sh;
      Wf[(((l * 2 + 1) * 4 + kk) * 8 + ot) * 512 + within] = (short)sm;
    } else {
      int jdx = i - 32768;
      int o = jdx >> 8, c = jdx & 255;
      float w = m1w[o * 259 + 3 + c];
      unsigned sh, sm;
      split2rn(w, sh, sm);
      int ot = o >> 4, mm = o & 15, kk = c >> 5, q = (c & 31) >> 3, j = c & 7;
      int within = (q * 16 + mm) * 8 + j;
      Wf[65536 + ((kk) * 8 + ot) * 512 + within] = (short)sh;
      Wf[65536 + ((8 + kk) * 8 + ot) * 512 + within] = (short)sm;
    }
  }
}

// ---------------- fps+ball: DPP in-wave reduce, LDS cross-wave combine ------------
// 4 pts/lane (no spill); one barrier/iter; all 4 waves then run the ball query.
__global__ __launch_bounds__(256, 1) void fps_ball_kernel(const float* __restrict__ xyz,
    float* __restrict__ xc, float* __restrict__ nxyz, float* __restrict__ agg,
    int* __restrict__ bidx, int* __restrict__ counts)
{
  __shared__ float sx0[1024], sx1[1024], sx2[1024];
  __shared__ float scen[384];
  __shared__ int slot[2][4][8];    // [parity][wave][{dbits, 1023-i, x, y, z, pad}]
  int bk = blockIdx.x, t = threadIdx.x;
  int b = bk / 19, k = bk % 19;
  int wave = t >> 6, lane = t & 63;

  float x0[4], x1[4], x2[4], dist[4];
#pragma unroll
  for (int j = 0; j < 4; ++j) {
    int i = j * 256 + t;
    const float* src = xyz + ((size_t)((b * 1024 + i) * 19 + k)) * 3;
    x0[j] = src[0]; x1[j] = src[1]; x2[j] = src[2];
    sx0[i] = x0[j]; sx1[i] = x1[j]; sx2[i] = x2[j];
    xc[(bk * 3 + 0) * 1024 + i] = x0[j];
    xc[(bk * 3 + 1) * 1024 + i] = x1[j];
    xc[(bk * 3 + 2) * 1024 + i] = x2[j];
    dist[j] = 1e10f;
  }
  if (t == 0) {
    int* s = &slot[0][0][0];
    s[0] = 0; s[1] = 1023;                        // index 0
    s[2] = __float_as_int(x0[0]);
    s[3] = __float_as_int(x1[0]);
    s[4] = __float_as_int(x2[0]);
#pragma unroll
    for (int w = 1; w < 4; ++w)
      *(v4i*)&slot[0][w][0] = *(v4i*)s, slot[0][w][4] = s[4];
  }
  __syncthreads();

  for (int it = 0; it < 128; ++it) {
    int pi = it & 1;
    // ---- combine 4 wave candidates (all threads, registers) ----
    v4i s0 = *(const v4i*)&slot[pi][0][0]; int z0 = slot[pi][0][4];
    v4i s1 = *(const v4i*)&slot[pi][1][0]; int z1 = slot[pi][1][4];
    v4i s2 = *(const v4i*)&slot[pi][2][0]; int z2 = slot[pi][2][4];
    v4i s3 = *(const v4i*)&slot[pi][3][0]; int z3 = slot[pi][3][4];
    unsigned long long k0 = ((unsigned long long)(unsigned)s0.x << 32) | (unsigned)s0.y;
    unsigned long long k1 = ((unsigned long long)(unsigned)s1.x << 32) | (unsigned)s1.y;
    unsigned long long k2 = ((unsigned long long)(unsigned)s2.x << 32) | (unsigned)s2.y;
    unsigned long long k3 = ((unsigned long long)(unsigned)s3.x << 32) | (unsigned)s3.y;
    if (k1 > k0) { k0 = k1; s0 = s1; z0 = z1; }
    if (k3 > k2) { k2 = k3; s2 = s3; z2 = z3; }
    if (k2 > k0) { k0 = k2; s0 = s2; z0 = z2; }
    float c0 = __int_as_float(s0.z);
    float c1 = __int_as_float(s0.w);
    float c2 = __int_as_float(z0);
    if (t < 3) {
      float cv = (t == 0) ? c0 : ((t == 1) ? c1 : c2);
      nxyz[(bk * 128 + it) * 3 + t] = cv;
      agg[(bk * 128 + it) * 3 + t]  = cv;
      scen[it * 3 + t] = cv;
    }
    // ---- update dists; per-lane first-max (i = j*256 + t ascending in j) ----
    float dbest = -1.f; int ibest = 0;
#pragma unroll
    for (int j = 0; j < 4; ++j) {
      float d = dist2f(x0[j], x1[j], x2[j], c0, c1, c2);
      float dj = fminf(dist[j], d);
      dist[j] = dj;
      if (dj > dbest) { dbest = dj; ibest = j * 256 + t; }
    }
    // ---- wave reduce via DPP: max dist, then max (1023-i) among achievers ----
    float dmax = wave_fmax(dbest);
    unsigned cand = (dbest == dmax) ? (unsigned)(1023 - ibest) : 0u;
    unsigned key = wave_umax(cand);
    // winner lane (unique: key encodes flat index) publishes the full record
    if (dbest == dmax && (unsigned)(1023 - ibest) == key) {
      int j = ibest >> 8;
      float wx = (j == 0) ? x0[0] : (j == 1) ? x0[1] : (j == 2) ? x0[2] : x0[3];
      float wy = (j == 0) ? x1[0] : (j == 1) ? x1[1] : (j == 2) ? x1[2] : x1[3];
      float wz = (j == 0) ? x2[0] : (j == 1) ? x2[1] : (j == 2) ? x2[2] : x2[3];
      int* s = &slot[pi ^ 1][wave][0];
      s[0] = __float_as_int(dmax);
      s[1] = (int)key;
      s[2] = __float_as_int(wx);
      s[3] = __float_as_int(wy);
      s[4] = __float_as_int(wz);
    }
    __syncthreads();
  }

  // ---- ball query: each wave handles 32 balls from LDS ----
  for (int p = wave * 32; p < wave * 32 + 32; ++p) {
    float c0 = scen[p * 3 + 0], c1 = scen[p * 3 + 1], c2 = scen[p * 3 + 2];
    int* outp = bidx + ((size_t)(bk * 128 + p)) * 128;
    int count = 0, first = 0;
    bool got = false;
    for (int ch = 0; ch < 16 && count < 128; ++ch) {
      int m = (ch << 6) + lane;
      float d = dist2f(sx0[m], sx1[m], sx2[m], c0, c1, c2);
      bool flag = d < 0.0225f;                 // strict fp32, RADIUS^2
      unsigned long long mask = __ballot(flag);
      if (!got && mask) { first = (ch << 6) + __builtin_ctzll(mask); got = true; }
      int pos = count + (int)__popcll(mask & ((1ull << lane) - 1ull));
      if (flag && pos < 128) outp[pos] = m;
      count += (int)__popcll(mask);
    }
    for (int j = count + lane; j < 128; j += 64) outp[j] = first;
    if (lane == 0) counts[bk * 128 + p] = count > 128 ? 128 : count;
  }
}

// ---------------- W1f: per-bk layer-1 feature GEMM via split2 MFMA ----------------
__global__ __launch_bounds__(256, 2) void w1f_kernel(
    const float* __restrict__ feats, const float* __restrict__ m1b,
    const float* __restrict__ prep, const short* __restrict__ Wf,
    float* __restrict__ W1f)
{
  __shared__ __align__(16) short ffrag[16384];    // 32KB
  int blk = blockIdx.x;
  int bk = blk >> 3, m0 = (blk & 7) << 7;
  int b = bk / 19, k = bk % 19;
  int t = threadIdx.x;
  int wave = t >> 6, lane = t & 63;
  int quad = lane >> 4, nl = lane & 15;
  int mloc = t & 127, chalf = t >> 7;
  int st_w = mloc >> 4, sl_w = mloc & 15;
  const float* fbase = feats + ((size_t)(b * 4864 + k)) * 1024 + m0 + mloc;
  const short* WA = Wf + 65536;

  f32x4 acc[2][8];
#pragma unroll
  for (int oi = 0; oi < 2; ++oi)
#pragma unroll
    for (int st = 0; st < 8; ++st) acc[oi][st] = (f32x4){0.f, 0.f, 0.f, 0.f};

  for (int ch = 0; ch < 4; ++ch) {
    int cbase = ch * 64 + chalf * 32;
#pragma unroll
    for (int g = 0; g < 4; ++g) {
      float v[8];
#pragma unroll
      for (int j = 0; j < 8; ++j)
        v[j] = fbase[(size_t)(cbase + g * 8 + j) * 19456];
      unsigned sh[8], sm[8];
#pragma unroll
      for (int j = 0; j < 8; ++j) split2rn(v[j], sh[j], sm[j]);
      int base = chalf * 4096 + st_w * 512 + (g * 16 + sl_w) * 8;
      v4i ph = {(int)(sh[0] | (sh[1] << 16)), (int)(sh[2] | (sh[3] << 16)),
                (int)(sh[4] | (sh[5] << 16)), (int)(sh[6] | (sh[7] << 16))};
      *(v4i*)&ffrag[base] = ph;
      v4i pm = {(int)(sm[0] | (sm[1] << 16)), (int)(sm[2] | (sm[3] << 16)),
                (int)(sm[4] | (sm[5] << 16)), (int)(sm[6] | (sm[7] << 16))};
      *(v4i*)&ffrag[base + 8192] = pm;
    }
    __syncthreads();
#pragma unroll
    for (int kkl = 0; kkl < 2; ++kkl) {
      int kk = ch * 2 + kkl;
      bf16x8 a[2][2];
#pragma unroll
      for (int oi = 0; oi < 2; ++oi)
#pragma unroll
        for (int sp = 0; sp < 2; ++sp)
          a[oi][sp] = *(const bf16x8*)(WA + ((sp * 8 + kk) * 8 + wave * 2 + oi) * 512 + lane * 8);
#pragma unroll
      for (int st = 0; st < 8; ++st) {
        const short* hb = ffrag + kkl * 4096 + st * 512 + lane * 8;
        bf16x8 b0 = *(const bf16x8*)hb;
        bf16x8 b1 = *(const bf16x8*)(hb + 8192);
#pragma unroll
        for (int oi = 0; oi < 2; ++oi) {
          f32x4 c = acc[oi][st];
          c = __builtin_amdgcn_mfma_f32_16x16x32_bf16(a[oi][1], b0, c, 0, 0, 0);
          c = __builtin_amdgcn_mfma_f32_16x16x32_bf16(a[oi][0], b1, c, 0, 0, 0);
          c = __builtin_amdgcn_mfma_f32_16x16x32_bf16(a[oi][0], b0, c, 0, 0, 0);
          acc[oi][st] = c;
        }
      }
    }
    __syncthreads();
  }
#pragma unroll
  for (int oi = 0; oi < 2; ++oi) {
    int o0 = (wave * 2 + oi) * 16 + quad * 4;
    float4 bb = *(const float4*)&m1b[o0];
    float4 al = *(const float4*)&prep[o0];
#pragma unroll
    for (int st = 0; st < 8; ++st) {
      int m_out = m0 + st * 16 + nl;
      f32x4 cc = acc[oi][st];
      float4 r;
      r.x = (cc[0] + bb.x) * al.x;
      r.y = (cc[1] + bb.y) * al.y;
      r.z = (cc[2] + bb.z) * al.z;
      r.w = (cc[3] + bb.w) * al.w;
      *(float4*)&W1f[((size_t)(bk * 1024 + m_out)) * 128 + o0] = r;
    }
  }
}

// ---------------- MFMA GEMM over one 128(c) x nst_h*16(s) fragment buffer ----------
__device__ __forceinline__ void mfma_layer(const short* __restrict__ Wf,
                                           const short* hfrag, int l,
                                           int wave, int lane, int nst_h,
                                           f32x4 acc[2][4])
{
#pragma unroll 1
  for (int kk = 0; kk < 4; ++kk) {
    bf16x8 a[2][2];
#pragma unroll
    for (int oi = 0; oi < 2; ++oi)
#pragma unroll
      for (int sp = 0; sp < 2; ++sp)
        a[oi][sp] = *(const bf16x8*)(Wf + (((l * 2 + sp) * 4 + kk) * 8 + (wave * 2 + oi)) * 512 + lane * 8);
    for (int st = 0; st < nst_h; ++st) {
      const short* hb = hfrag + kk * 2048 + st * 512 + lane * 8;
      bf16x8 b0 = *(const bf16x8*)(hb);           // hi
      bf16x8 b1 = *(const bf16x8*)(hb + 8192);    // mid
#pragma unroll
      for (int oi = 0; oi < 2; ++oi) {
        f32x4 c = acc[oi][st];
        c = __builtin_amdgcn_mfma_f32_16x16x32_bf16(a[oi][1], b0, c, 0, 0, 0);
        c = __builtin_amdgcn_mfma_f32_16x16x32_bf16(a[oi][0], b1, c, 0, 0, 0);
        c = __builtin_amdgcn_mfma_f32_16x16x32_bf16(a[oi][0], b0, c, 0, 0, 0);
        acc[oi][st] = c;
      }
    }
  }
}

// ---------------- fused SA: 4 balls per block, tiles packed over passes ----------
__global__ __launch_bounds__(256, 3) void sa_kernel(
    const float* __restrict__ xc, const float* __restrict__ nxyz,
    const int* __restrict__ bidx, const int* __restrict__ counts,
    const float* __restrict__ W1f, const float* __restrict__ prep,
    const short* __restrict__ Wf, float* __restrict__ feat_out)
{
  __shared__ __align__(16) short hfrag[16384];   // 32KB
  __shared__ float pcs[512];
  __shared__ float sm[32 * 128];                 // 16KB per-tile o-max
  __shared__ float ccen[12];
  __shared__ int scnt[4];
  int gb = blockIdx.x, bk = gb >> 5, pb = (gb & 31) << 2;
  int t = threadIdx.x;
  int wave = t >> 6, lane = t & 63;
  int quad = lane >> 4, nl = lane & 15;

  pcs[t] = prep[1280 + t];
  pcs[256 + t] = prep[1536 + t];
  if (t < 4) scnt[t] = counts[bk * 128 + pb + t];
  if (t < 12) {
    int bb = t / 3, c = t % 3;
    ccen[t] = nxyz[(bk * 128 + pb + bb) * 3 + c];
  }
  __syncthreads();
  int n0 = (scnt[0] + 15) >> 4, n1 = (scnt[1] + 15) >> 4;
  int n2 = (scnt[2] + 15) >> 4, n3 = (scnt[3] + 15) >> 4;
  int pf1 = n0, pf2 = n0 + n1, pf3 = n0 + n1 + n2, T = n0 + n1 + n2 + n3;

  for (int q0 = 0; q0 < T; q0 += 4) {
    int nst_h = T - q0;
    if (nst_h > 4) nst_h = 4;
    // ---- h1 build ----
    {
      int cg = wave;
      int st = lane >> 4, sl = lane & 15;
      if (st < nst_h) {
        int q = q0 + st;
        int bq = (q >= pf1) + (q >= pf2) + (q >= pf3);
        int tstart = (bq == 0) ? 0 : (bq == 1) ? pf1 : (bq == 2) ? pf2 : pf3;
        int tslot = q - tstart;
        int m = bidx[((size_t)(bk * 128 + pb + bq)) * 128 + tslot * 16 + sl];
        float cen0 = ccen[bq * 3 + 0], cen1 = ccen[bq * 3 + 1], cen2 = ccen[bq * 3 + 2];
        float g0 = (xc[(bk * 3 + 0) * 1024 + m] - cen0) * (1.0f / 0.15f);
        float g1 = (xc[(bk * 3 + 1) * 1024 + m] - cen1) * (1.0f / 0.15f);
        float g2 = (xc[(bk * 3 + 2) * 1024 + m] - cen2) * (1.0f / 0.15f);
        const float4* wrow = (const float4*)(W1f + ((size_t)(bk * 1024 + m)) * 128 + cg * 32);
        const float4* pcp = (const float4*)pcs + cg * 32;
#pragma unroll
        for (int g = 0; g < 4; ++g) {
          float4 wva = wrow[g * 2], wvb = wrow[g * 2 + 1];
          float wv[8] = {wva.x, wva.y, wva.z, wva.w, wvb.x, wvb.y, wvb.z, wvb.w};
          unsigned sh[8], smv[8];
#pragma unroll
          for (int e = 0; e < 8; ++e) {
            float4 pc = pcp[g * 8 + e];
            float hv = fmaxf(wv[e] + pc.x * g0 + pc.y * g1 + pc.z * g2 + pc.w, 0.f);
            split2rn(hv, sh[e], smv[e]);
          }
          int base = (cg * 4 + st) * 512 + (g * 16 + sl) * 8;
          v4i ph = {(int)(sh[0] | (sh[1] << 16)), (int)(sh[2] | (sh[3] << 16)),
                    (int)(sh[4] | (sh[5] << 16)), (int)(sh[6] | (sh[7] << 16))};
          *(v4i*)&hfrag[base] = ph;
          v4i pm = {(int)(smv[0] | (smv[1] << 16)), (int)(smv[2] | (smv[3] << 16)),
                    (int)(smv[4] | (smv[5] << 16)), (int)(smv[6] | (smv[7] << 16))};
          *(v4i*)&hfrag[base + 8192] = pm;
        }
      }
    }
    __syncthreads();

    // ---- layer 2 ----
    f32x4 acc[2][4];
#pragma unroll
    for (int oi = 0; oi < 2; ++oi)
#pragma unroll
      for (int st = 0; st < 4; ++st) acc[oi][st] = (f32x4){0.f, 0.f, 0.f, 0.f};
    mfma_layer(Wf, hfrag, 0, wave, lane, nst_h, acc);
    __syncthreads();

    // ---- h2 epilogue ----
#pragma unroll
    for (int oi = 0; oi < 2; ++oi) {
      int o0 = (wave * 2 + oi) * 16 + quad * 4;
      float4 al = *(const float4*)&prep[256 + o0];
      float4 be = *(const float4*)&prep[384 + o0];
      int kk2 = o0 >> 5, g2 = (o0 & 31) >> 3, j0 = o0 & 7;
      for (int st = 0; st < nst_h; ++st) {
        f32x4 cc = acc[oi][st];
        float v0 = fmaxf(fmaf(cc[0], al.x, be.x), 0.f);
        float v1 = fmaxf(fmaf(cc[1], al.y, be.y), 0.f);
        float v2 = fmaxf(fmaf(cc[2], al.z, be.z), 0.f);
        float v3 = fmaxf(fmaf(cc[3], al.w, be.w), 0.f);
        unsigned h0, m0_, h1, m1_, h2, m2_, h3, m3_;
        split2rn(v0, h0, m0_); split2rn(v1, h1, m1_);
        split2rn(v2, h2, m2_); split2rn(v3, h3, m3_);
        int base = (kk2 * 4 + st) * 512 + (g2 * 16 + nl) * 8 + j0;
        v2i w0 = {(int)(h0 | (h1 << 16)), (int)(h2 | (h3 << 16))};
        *(v2i*)&hfrag[base] = w0;
        v2i w1 = {(int)(m0_ | (m1_ << 16)), (int)(m2_ | (m3_ << 16))};
        *(v2i*)&hfrag[base + 8192] = w1;
      }
    }
    __syncthreads();

    // ---- layer 3 ----
#pragma unroll
    for (int oi = 0; oi < 2; ++oi)
#pragma unroll
      for (int st = 0; st < 4; ++st) acc[oi][st] = (f32x4){0.f, 0.f, 0.f, 0.f};
    mfma_layer(Wf, hfrag, 1, wave, lane, nst_h, acc);

    // ---- layer-3 epilogue: BN+ReLU, quad-reduce max per tile ----
#pragma unroll
    for (int oi = 0; oi < 2; ++oi) {
      int o0 = (wave * 2 + oi) * 16 + quad * 4;
      float4 al = *(const float4*)&prep[512 + o0];
      float4 be = *(const float4*)&prep[640 + o0];
      for (int st = 0; st < nst_h; ++st) {
        f32x4 cc = acc[oi][st];
        float v[4];
        v[0] = fmaxf(fmaf(cc[0], al.x, be.x), 0.f);
        v[1] = fmaxf(fmaf(cc[1], al.y, be.y), 0.f);
        v[2] = fmaxf(fmaf(cc[2], al.z, be.z), 0.f);
        v[3] = fmaxf(fmaf(cc[3], al.w, be.w), 0.f);
#pragma unroll
        for (int r = 0; r < 4; ++r) {
          float x = v[r];
          x = fmaxf(x, __shfl_xor(x, 1));
          x = fmaxf(x, __shfl_xor(x, 2));
          x = fmaxf(x, __shfl_xor(x, 4));
          x = fmaxf(x, __shfl_xor(x, 8));
          if (nl == 0) sm[(q0 + st) * 128 + o0 + r] = x;
        }
      }
    }
    __syncthreads();
  }

  // ---- final: merge tiles per ball, write feat ----
#pragma unroll
  for (int e = t; e < 512; e += 256) {
    int bb = e >> 7, o = e & 127;
    int qs = (bb == 0) ? 0 : (bb == 1) ? pf1 : (bb == 2) ? pf2 : pf3;
    int nq = (bb == 0) ? n0 : (bb == 1) ? n1 : (bb == 2) ? n2 : n3;
    float v = sm[qs * 128 + o];
    for (int q = 1; q < nq; ++q) v = fmaxf(v, sm[(qs + q) * 128 + o]);
    feat_out[(((size_t)bk) << 14) + (o << 7) + pb + bb] = v;
  }
}

// ---------------- head: c1 -> c2 (split2 MFMA) -> op -> scores; 2 blocks/bk ------
__global__ __launch_bounds__(256) void head_kernel(const float* __restrict__ featg,
    const float* __restrict__ prep, const short* __restrict__ Wf,
    const float* __restrict__ nxyz, const float* __restrict__ opw,
    const float* __restrict__ opb, float* __restrict__ scores)
{
  __shared__ __align__(16) short hfrag[16384];   // 32KB frags (128c x 64p)
  __shared__ float hplain[128 * 65];             // 33.3KB, stride 65 vs conflicts
  int bk = blockIdx.x >> 1, p0 = (blockIdx.x & 1) << 6;
  int t = threadIdx.x;
  int wave = t >> 6, lane = t & 63;
  int quad = lane >> 4, nl = lane & 15;
  const short* WC = Wf + 131072;

  // ---- stage feat[c][p0..p0+63] into split2 B-frags ----
  {
    int cg = wave;                                // 32 channels per wave
    int st = lane >> 4, sl = lane & 15;           // p tile/slot
    const float* fb = featg + (bk << 14) + p0 + lane;
#pragma unroll
    for (int g = 0; g < 4; ++g) {
      float v[8];
#pragma unroll
      for (int e = 0; e < 8; ++e)
        v[e] = fb[(cg * 32 + g * 8 + e) << 7];
      unsigned sh[8], sm[8];
#pragma unroll
      for (int e = 0; e < 8; ++e) split2rn(v[e], sh[e], sm[e]);
      int base = (cg * 4 + st) * 512 + (g * 16 + sl) * 8;
      v4i ph = {(int)(sh[0] | (sh[1] << 16)), (int)(sh[2] | (sh[3] << 16)),
                (int)(sh[4] | (sh[5] << 16)), (int)(sh[6] | (sh[7] << 16))};
      *(v4i*)&hfrag[base] = ph;
      v4i pm = {(int)(sm[0] | (sm[1] << 16)), (int)(sm[2] | (sm[3] << 16)),
                (int)(sm[4] | (sm[5] << 16)), (int)(sm[6] | (sm[7] << 16))};
      *(v4i*)&hfrag[base + 8192] = pm;
    }
  }
  __syncthreads();

  // ---- c1 ----
  f32x4 acc[2][4];
#pragma unroll
  for (int oi = 0; oi < 2; ++oi)
#pragma unroll
    for (int st = 0; st < 4; ++st) acc[oi][st] = (f32x4){0.f, 0.f, 0.f, 0.f};
  mfma_layer(WC, hfrag, 0, wave, lane, 4, acc);
  __syncthreads();

  // ---- c1 epilogue: BN+ReLU, write back frags ----
#pragma unroll
  for (int oi = 0; oi < 2; ++oi) {
    int o0 = (wave * 2 + oi) * 16 + quad * 4;
    float4 al = *(const float4*)&prep[768 + o0];
    float4 be = *(const float4*)&prep[896 + o0];
    int kk2 = o0 >> 5, g2 = (o0 & 31) >> 3, j0 = o0 & 7;
#pragma unroll
    for (int st = 0; st < 4; ++st) {
      f32x4 cc = acc[oi][st];
      float v0 = fmaxf(fmaf(cc[0], al.x, be.x), 0.f);
      float v1 = fmaxf(fmaf(cc[1], al.y, be.y), 0.f);
      float v2 = fmaxf(fmaf(cc[2], al.z, be.z), 0.f);
      float v3 = fmaxf(fmaf(cc[3], al.w, be.w), 0.f);
      unsigned h0, m0_, h1, m1_, h2, m2_, h3, m3_;
      split2rn(v0, h0, m0_); split2rn(v1, h1, m1_);
      split2rn(v2, h2, m2_); split2rn(v3, h3, m3_);
      int base = (kk2 * 4 + st) * 512 + (g2 * 16 + nl) * 8 + j0;
      v2i w0 = {(int)(h0 | (h1 << 16)), (int)(h2 | (h3 << 16))};
      *(v2i*)&hfrag[base] = w0;
      v2i w1 = {(int)(m0_ | (m1_ << 16)), (int)(m2_ | (m3_ << 16))};
      *(v2i*)&hfrag[base + 8192] = w1;
    }
  }
  __syncthreads();

  // ---- c2 ----
#pragma unroll
  for (int oi = 0; oi < 2; ++oi)
#pragma unroll
    for (int st = 0; st < 4; ++st) acc[oi][st] = (f32x4){0.f, 0.f, 0.f, 0.f};
  mfma_layer(WC, hfrag, 1, wave, lane, 4, acc);

  // ---- c2 epilogue: BN+ReLU -> hplain[c][p] ----
#pragma unroll
  for (int oi = 0; oi < 2; ++oi) {
    int o0 = (wave * 2 + oi) * 16 + quad * 4;
    float4 al = *(const float4*)&prep[1024 + o0];
    float4 be = *(const float4*)&prep[1152 + o0];
#pragma unroll
    for (int st = 0; st < 4; ++st) {
      f32x4 cc = acc[oi][st];
      int p = st * 16 + nl;
      hplain[(o0 + 0) * 65 + p] = fmaxf(fmaf(cc[0], al.x, be.x), 0.f);
      hplain[(o0 + 1) * 65 + p] = fmaxf(fmaf(cc[1], al.y, be.y), 0.f);
      hplain[(o0 + 2) * 65 + p] = fmaxf(fmaf(cc[2], al.z, be.z), 0.f);
      hplain[(o0 + 3) * 65 + p] = fmaxf(fmaf(cc[3], al.w, be.w), 0.f);
    }
  }
  __syncthreads();

  // ---- op head + scores ----
  if (t < 64) {
    int p = t, k = bk % 19;
    float res[5];
#pragma unroll
    for (int j = 0; j < 5; ++j) {
      const float* wr = opw + ((size_t)(k * 5 + j)) * 128;
      float a = opb[k * 5 + j];
      for (int c = 0; c < 128; ++c) a = fmaf(wr[c], hplain[c * 65 + p], a);
      res[j] = a;
    }
    int pg = p0 + p;
    float a0 = nxyz[(bk * 128 + pg) * 3 + 0];
    float a1 = nxyz[(bk * 128 + pg) * 3 + 1];
    float a2 = nxyz[(bk * 128 + pg) * 3 + 2];
    float* sc = scores + ((size_t)(bk * 128 + pg)) * 5;
    sc[0] = res[0];
    sc[1] = res[1];
    sc[2] = a0 + res[2];
    sc[3] = a1 + res[3];
    sc[4] = a2 + res[4];
  }
}

extern "C" void kernel_launch(void* const* d_in, const int* in_sizes, int n_in,
                              void* d_out, int out_size, void* d_ws, size_t ws_size,
                              hipStream_t stream) {
  (void)in_sizes; (void)n_in; (void)out_size; (void)ws_size;
  const float* xyz  = (const float*)d_in[0];
  const float* fts  = (const float*)d_in[1];
  const float* m1w  = (const float*)d_in[2];
  const float* m1b  = (const float*)d_in[3];
  const float* m1g  = (const float*)d_in[4];
  const float* m1be = (const float*)d_in[5];
  const float* m2w  = (const float*)d_in[6];
  const float* m2b  = (const float*)d_in[7];
  const float* m2g  = (const float*)d_in[8];
  const float* m2be = (const float*)d_in[9];
  const float* m3w  = (const float*)d_in[10];
  const float* m3b  = (const float*)d_in[11];
  const float* m3g  = (const float*)d_in[12];
  const float* m3be = (const float*)d_in[13];
  const float* c1w  = (const float*)d_in[14];
  const float* c1b  = (const float*)d_in[15];
  const float* c1g  = (const float*)d_in[16];
  const float* c1be = (const float*)d_in[17];
  const float* c2w  = (const float*)d_in[18];
  const float* c2b  = (const float*)d_in[19];
  const float* c2g  = (const float*)d_in[20];
  const float* c2be = (const float*)d_in[21];
  const float* opw  = (const float*)d_in[22];
  const float* opb  = (const float*)d_in[23];

  float* out = (float*)d_out;
  char* ws = (char*)d_ws;
  float* xc   = (float*)(ws + OFF_XC);
  float* nxyz = (float*)(ws + OFF_NXYZ);
  int*   bidx = (int*)(ws + OFF_BIDX);
  float* W1f  = (float*)(ws + OFF_W1F);
  float* prep = (float*)(ws + OFF_PREP);
  short* Wf   = (short*)(ws + OFF_WF);
  int*   cnt  = (int*)(ws + OFF_CNT);

  hipLaunchKernelGGL(prep_wsplit_kernel, dim3(97), dim3(256), 0, stream,
                     m1w, m1g, m1be, m2w, m2b, m2g, m2be, m3w, m3b, m3g, m3be,
                     c1w, c1b, c1g, c1be, c2w, c2b, c2g, c2be, prep, Wf);
  hipLaunchKernelGGL(fps_ball_kernel, dim3(NBK), dim3(256), 0, stream,
                     xyz, xc, nxyz, out + OUT_AGG, bidx, cnt);
  hipLaunchKernelGGL(w1f_kernel, dim3(NBK * 8), dim3(256), 0, stream,
                     fts, m1b, prep, Wf, W1f);
  hipLaunchKernelGGL(sa_kernel, dim3(NBK * 32), dim3(256), 0, stream,
                     xc, nxyz, bidx, cnt, W1f, prep, Wf, out + OUT_FEAT);
  hipLaunchKernelGGL(head_kernel, dim3(NBK * 2), dim3(256), 0, stream,
                     out + OUT_FEAT, prep, Wf, nxyz, opw, opb, out);
}

// Round 8
// 332.996 us; speedup vs baseline: 1.1349x; 1.0888x over previous
//
#include <hip/hip_runtime.h>
#include <math.h>

// ---------------- problem constants ----------------
// B=2, K=19 -> BK=38 batches; M=1024 points; C=256 feat ch; NPOINT=NSAMPLE=128
#define NBK   38

// ---------------- workspace layout (bytes) ----------------
#define OFF_XC    0u          // [38][3][1024] f32        = 466944
#define OFF_NXYZ  466944u     // [38][128][3]  f32        = 58368
#define OFF_BIDX  525312u     // [38][128][128] i32       = 2490368
#define OFF_W1F   3015680u    // [38][1024][128] f32      = 19922944
#define OFF_PREP  22938624u   // 4096 f32
#define OFF_WF    22955008u   // 196608 shorts: w2/w3 (0), w1feat (65536), c1/c2 (131072)
#define OFF_CNT   23348224u   // [38][128] i32 ball counts = 19456

// ---------------- d_out layout (float offsets) ----------------
#define OUT_AGG   24320       // scores at 0: (2,19,128,5)
#define OUT_FEAT  38912       // agg: (2,19,128,3), feat: (2,19,128,128)

typedef short bf16x8 __attribute__((ext_vector_type(8)));   // 8 bf16 = 4 VGPR
typedef float f32x4  __attribute__((ext_vector_type(4)));
typedef int   v4i    __attribute__((ext_vector_type(4)));
typedef int   v2i    __attribute__((ext_vector_type(2)));

// exact IEEE fp32 squared distance, no FMA contraction, ((d0^2+d1^2)+d2^2)
__device__ __forceinline__ float dist2f(float a0, float a1, float a2,
                                        float b0, float b1, float b2) {
#pragma clang fp contract(off)
  float d0 = a0 - b0;
  float d1 = a1 - b1;
  float d2 = a2 - b2;
  return d0 * d0 + d1 * d1 + d2 * d2;
}

// 2-way bf16 split with round-to-nearest-even: v ~= hi + mid, residual <= 2^-18 |v|
__device__ __forceinline__ void split2rn(float v, unsigned& sh, unsigned& sm) {
  unsigned u = __float_as_uint(v);
  unsigned rh = (u + 0x7fffu + ((u >> 16) & 1u)) & 0xffff0000u;
  sh = rh >> 16;
  float r1 = v - __uint_as_float(rh);        // exact in fp32
  unsigned u1 = __float_as_uint(r1);
  unsigned rm = (u1 + 0x7fffu + ((u1 >> 16) & 1u)) & 0xffff0000u;
  sm = rm >> 16;
}

// DPP reduce steps (ALU-speed cross-lane; lane 63 ends with the full reduction)
template<int CTRL, int RMASK>
__device__ __forceinline__ float fmax_dpp(float x) {
  int o = __builtin_amdgcn_update_dpp(__float_as_int(x), __float_as_int(x),
                                      CTRL, RMASK, 0xf, false);
  return fmaxf(x, __int_as_float(o));
}
template<int CTRL, int RMASK>
__device__ __forceinline__ unsigned umax_dpp(unsigned x) {
  unsigned o = (unsigned)__builtin_amdgcn_update_dpp((int)x, (int)x,
                                                     CTRL, RMASK, 0xf, false);
  return o > x ? o : x;
}
__device__ __forceinline__ float wave_fmax(float x) {
  x = fmax_dpp<0x111, 0xf>(x);
  x = fmax_dpp<0x112, 0xf>(x);
  x = fmax_dpp<0x114, 0xf>(x);
  x = fmax_dpp<0x118, 0xf>(x);
  x = fmax_dpp<0x142, 0xa>(x);
  x = fmax_dpp<0x143, 0xc>(x);
  return __int_as_float(__builtin_amdgcn_readlane(__float_as_int(x), 63));
}
__device__ __forceinline__ unsigned wave_umax(unsigned x) {
  x = umax_dpp<0x111, 0xf>(x);
  x = umax_dpp<0x112, 0xf>(x);
  x = umax_dpp<0x114, 0xf>(x);
  x = umax_dpp<0x118, 0xf>(x);
  x = umax_dpp<0x142, 0xa>(x);
  x = umax_dpp<0x143, 0xc>(x);
  return (unsigned)__builtin_amdgcn_readlane((int)x, 63);
}

// ---------------- K1 "front": fps_ball | w1f | wsplit | csplit | prep ------------
// blocks 0..37: fps+ball; 38..341: w1f; 342..405: w2/w3/w1 split;
// 406..437: c1/c2 split; 438: prep constants. All mutually independent.
__global__ __launch_bounds__(256, 2) void front_kernel(
    const float* __restrict__ xyz, const float* __restrict__ feats,
    const float* __restrict__ m1w, const float* __restrict__ m1b,
    const float* __restrict__ m1g, const float* __restrict__ m1be,
    const float* __restrict__ m2w, const float* __restrict__ m2b,
    const float* __restrict__ m2g, const float* __restrict__ m2be,
    const float* __restrict__ m3w, const float* __restrict__ m3b,
    const float* __restrict__ m3g, const float* __restrict__ m3be,
    const float* __restrict__ c1w, const float* __restrict__ c1b,
    const float* __restrict__ c1g, const float* __restrict__ c1be,
    const float* __restrict__ c2w, const float* __restrict__ c2b,
    const float* __restrict__ c2g, const float* __restrict__ c2be,
    float* __restrict__ xc, float* __restrict__ nxyz, float* __restrict__ agg,
    int* __restrict__ bidx, int* __restrict__ counts,
    float* __restrict__ W1f, short* __restrict__ Wf, float* __restrict__ prep)
{
  __shared__ __align__(16) char smem[32768];
  int bid = blockIdx.x, t = threadIdx.x;
  int wave = t >> 6, lane = t & 63;

  if (bid < NBK) {
    // ================= fps + ball (no global ops inside the loop) =================
    int bk = bid;
    int b = bk / 19, k = bk % 19;
    float* sx0 = (float*)smem;                  // 1024 f32
    float* sx1 = sx0 + 1024;
    float* sx2 = sx1 + 1024;
    float* scen = sx2 + 1024;                   // 384 f32
    int* slot = (int*)(scen + 384);             // [2][4][8] ints

    float x0[4], x1[4], x2[4], dist[4];
#pragma unroll
    for (int j = 0; j < 4; ++j) {
      int i = j * 256 + t;
      const float* src = xyz + ((size_t)((b * 1024 + i) * 19 + k)) * 3;
      x0[j] = src[0]; x1[j] = src[1]; x2[j] = src[2];
      sx0[i] = x0[j]; sx1[i] = x1[j]; sx2[i] = x2[j];
      xc[(bk * 3 + 0) * 1024 + i] = x0[j];
      xc[(bk * 3 + 1) * 1024 + i] = x1[j];
      xc[(bk * 3 + 2) * 1024 + i] = x2[j];
      dist[j] = 1e10f;
    }
    if (t == 0) {
#pragma unroll
      for (int w = 0; w < 4; ++w) {
        int* s = slot + w * 8;
        s[0] = 0; s[1] = 1023;                  // index 0
        s[2] = __float_as_int(x0[0]);
        s[3] = __float_as_int(x1[0]);
        s[4] = __float_as_int(x2[0]);
      }
    }
    __syncthreads();

    for (int it = 0; it < 128; ++it) {
      int pi = it & 1;
      const int* sl = slot + pi * 32;
      // ---- combine 4 wave candidates (all threads, registers) ----
      v4i s0 = *(const v4i*)(sl + 0);  int z0 = sl[4];
      v4i s1 = *(const v4i*)(sl + 8);  int z1 = sl[12];
      v4i s2 = *(const v4i*)(sl + 16); int z2 = sl[20];
      v4i s3 = *(const v4i*)(sl + 24); int z3 = sl[28];
      unsigned long long k0 = ((unsigned long long)(unsigned)s0.x << 32) | (unsigned)s0.y;
      unsigned long long k1 = ((unsigned long long)(unsigned)s1.x << 32) | (unsigned)s1.y;
      unsigned long long k2 = ((unsigned long long)(unsigned)s2.x << 32) | (unsigned)s2.y;
      unsigned long long k3 = ((unsigned long long)(unsigned)s3.x << 32) | (unsigned)s3.y;
      if (k1 > k0) { k0 = k1; s0 = s1; z0 = z1; }
      if (k3 > k2) { k2 = k3; s2 = s3; z2 = z3; }
      if (k2 > k0) { k0 = k2; s0 = s2; z0 = z2; }
      float c0 = __int_as_float(s0.z);
      float c1 = __int_as_float(s0.w);
      float c2 = __int_as_float(z0);
      if (t < 3) scen[it * 3 + t] = (t == 0) ? c0 : ((t == 1) ? c1 : c2);
      // ---- update dists; per-lane first-max (i = j*256 + t, ascending j) ----
      float dbest = -1.f; int ibest = 0;
#pragma unroll
      for (int j = 0; j < 4; ++j) {
        float d = dist2f(x0[j], x1[j], x2[j], c0, c1, c2);
        float dj = fminf(dist[j], d);
        dist[j] = dj;
        if (dj > dbest) { dbest = dj; ibest = j * 256 + t; }
      }
      // ---- wave reduce via DPP: max dist, then max (1023-i) among achievers ----
      float dmax = wave_fmax(dbest);
      unsigned cand = (dbest == dmax) ? (unsigned)(1023 - ibest) : 0u;
      unsigned key = wave_umax(cand);
      // winner lane (unique: key encodes flat index) publishes the full record
      if (dbest == dmax && (unsigned)(1023 - ibest) == key) {
        int j = ibest >> 8;
        float wx = (j == 0) ? x0[0] : (j == 1) ? x0[1] : (j == 2) ? x0[2] : x0[3];
        float wy = (j == 0) ? x1[0] : (j == 1) ? x1[1] : (j == 2) ? x1[2] : x1[3];
        float wz = (j == 0) ? x2[0] : (j == 1) ? x2[1] : (j == 2) ? x2[2] : x2[3];
        int* s = slot + (pi ^ 1) * 32 + wave * 8;
        s[0] = __float_as_int(dmax);
        s[1] = (int)key;
        s[2] = __float_as_int(wx);
        s[3] = __float_as_int(wy);
        s[4] = __float_as_int(wz);
      }
      __syncthreads();
    }

    // ---- flush centers to global once ----
    for (int e = t; e < 384; e += 256) {
      float v = scen[e];
      nxyz[bk * 384 + e] = v;
      agg[bk * 384 + e]  = v;
    }

    // ---- ball query: each wave handles 32 balls from LDS ----
    for (int p = wave * 32; p < wave * 32 + 32; ++p) {
      float c0 = scen[p * 3 + 0], c1 = scen[p * 3 + 1], c2 = scen[p * 3 + 2];
      int* outp = bidx + ((size_t)(bk * 128 + p)) * 128;
      int count = 0, first = 0;
      bool got = false;
      for (int ch = 0; ch < 16 && count < 128; ++ch) {
        int m = (ch << 6) + lane;
        float d = dist2f(sx0[m], sx1[m], sx2[m], c0, c1, c2);
        bool flag = d < 0.0225f;                 // strict fp32, RADIUS^2
        unsigned long long mask = __ballot(flag);
        if (!got && mask) { first = (ch << 6) + __builtin_ctzll(mask); got = true; }
        int pos = count + (int)__popcll(mask & ((1ull << lane) - 1ull));
        if (flag && pos < 128) outp[pos] = m;
        count += (int)__popcll(mask);
      }
      for (int j = count + lane; j < 128; j += 64) outp[j] = first;
      if (lane == 0) counts[bk * 128 + p] = count > 128 ? 128 : count;
    }
    return;
  }

  if (bid < 342) {
    // ================= w1f (alpha1 inline; no prep/Wf-split dependency for bias) ==
    short* ffrag = (short*)smem;                  // 32KB
    int blk = bid - NBK;
    int bk = blk >> 3, m0 = (blk & 7) << 7;
    int b = bk / 19, k = bk % 19;
    int quad = lane >> 4, nl = lane & 15;
    int mloc = t & 127, chalf = t >> 7;
    int st_w = mloc >> 4, sl_w = mloc & 15;
    const float* fbase = feats + ((size_t)(b * 4864 + k)) * 1024 + m0 + mloc;
    const short* WA = Wf + 65536;                 // NOTE: needs wsplit... see below

    // w1 feature weights are split ON THE FLY (no dependency on wsplit blocks):
    // lane reads 8 consecutive c from m1w[o*259+3+c], o = ot*16+nl, c = kk*32+quad*8+j
    f32x4 acc[2][8];
#pragma unroll
    for (int oi = 0; oi < 2; ++oi)
#pragma unroll
      for (int st = 0; st < 8; ++st) acc[oi][st] = (f32x4){0.f, 0.f, 0.f, 0.f};

    for (int ch = 0; ch < 4; ++ch) {
      int cbase = ch * 64 + chalf * 32;
#pragma unroll
      for (int g = 0; g < 4; ++g) {
        float v[8];
#pragma unroll
        for (int j = 0; j < 8; ++j)
          v[j] = fbase[(size_t)(cbase + g * 8 + j) * 19456];
        unsigned sh[8], sm[8];
#pragma unroll
        for (int j = 0; j < 8; ++j) split2rn(v[j], sh[j], sm[j]);
        int base = chalf * 4096 + st_w * 512 + (g * 16 + sl_w) * 8;
        v4i ph = {(int)(sh[0] | (sh[1] << 16)), (int)(sh[2] | (sh[3] << 16)),
                  (int)(sh[4] | (sh[5] << 16)), (int)(sh[6] | (sh[7] << 16))};
        *(v4i*)&ffrag[base] = ph;
        v4i pm = {(int)(sm[0] | (sm[1] << 16)), (int)(sm[2] | (sm[3] << 16)),
                  (int)(sm[4] | (sm[5] << 16)), (int)(sm[6] | (sm[7] << 16))};
        *(v4i*)&ffrag[base + 8192] = pm;
      }
      __syncthreads();
#pragma unroll
      for (int kkl = 0; kkl < 2; ++kkl) {
        int kk = ch * 2 + kkl;
        bf16x8 a[2][2];
#pragma unroll
        for (int oi = 0; oi < 2; ++oi) {
          int o_row = (wave * 2 + oi) * 16 + nl;
          const float* wsrc = m1w + o_row * 259 + 3 + kk * 32 + quad * 8;
          float wv[8];
#pragma unroll
          for (int j = 0; j < 8; ++j) wv[j] = wsrc[j];
          unsigned sh[8], sm[8];
#pragma unroll
          for (int j = 0; j < 8; ++j) split2rn(wv[j], sh[j], sm[j]);
          short ah[8], am[8];
#pragma unroll
          for (int j = 0; j < 8; ++j) { ah[j] = (short)sh[j]; am[j] = (short)sm[j]; }
          a[oi][0] = (bf16x8){ah[0], ah[1], ah[2], ah[3], ah[4], ah[5], ah[6], ah[7]};
          a[oi][1] = (bf16x8){am[0], am[1], am[2], am[3], am[4], am[5], am[6], am[7]};
        }
#pragma unroll
        for (int st = 0; st < 8; ++st) {
          const short* hb = ffrag + kkl * 4096 + st * 512 + lane * 8;
          bf16x8 b0 = *(const bf16x8*)hb;
          bf16x8 b1 = *(const bf16x8*)(hb + 8192);
#pragma unroll
          for (int oi = 0; oi < 2; ++oi) {
            f32x4 c = acc[oi][st];
            c = __builtin_amdgcn_mfma_f32_16x16x32_bf16(a[oi][1], b0, c, 0, 0, 0);
            c = __builtin_amdgcn_mfma_f32_16x16x32_bf16(a[oi][0], b1, c, 0, 0, 0);
            c = __builtin_amdgcn_mfma_f32_16x16x32_bf16(a[oi][0], b0, c, 0, 0, 0);
            acc[oi][st] = c;
          }
        }
      }
      __syncthreads();
    }
    (void)WA;
    float inv = 1.0f / sqrtf(1.0f + 1e-5f);
#pragma unroll
    for (int oi = 0; oi < 2; ++oi) {
      int o0 = (wave * 2 + oi) * 16 + quad * 4;
      float4 bb = *(const float4*)&m1b[o0];
      float4 gg = *(const float4*)&m1g[o0];
#pragma unroll
      for (int st = 0; st < 8; ++st) {
        int m_out = m0 + st * 16 + nl;
        f32x4 cc = acc[oi][st];
        float4 r;
        r.x = (cc[0] + bb.x) * (gg.x * inv);
        r.y = (cc[1] + bb.y) * (gg.y * inv);
        r.z = (cc[2] + bb.z) * (gg.z * inv);
        r.w = (cc[3] + bb.w) * (gg.w * inv);
        *(float4*)&W1f[((size_t)(bk * 1024 + m_out)) * 128 + o0] = r;
      }
    }
    return;
  }

  if (bid < 406) {
    // ================= w2/w3 + w1feat split =================
    int idx = (bid - 342) * 256 + t;               // 0..16383
#pragma unroll
    for (int e = 0; e < 4; ++e) {
      int i = idx * 4 + e;                         // 0..65535
      if (i < 32768) {
        int c = i & 127, o = (i >> 7) & 127, l = i >> 14;
        float w = (l ? m3w : m2w)[o * 128 + c];
        unsigned sh, sm;
        split2rn(w, sh, sm);
        int ot = o >> 4, mm = o & 15, kk = c >> 5, q = (c & 31) >> 3, j = c & 7;
        int within = (q * 16 + mm) * 8 + j;
        Wf[(((l * 2 + 0) * 4 + kk) * 8 + ot) * 512 + within] = (short)sh;
        Wf[(((l * 2 + 1) * 4 + kk) * 8 + ot) * 512 + within] = (short)sm;
      } else {
        int jdx = i - 32768;
        int o = jdx >> 8, c = jdx & 255;
        float w = m1w[o * 259 + 3 + c];
        unsigned sh, sm;
        split2rn(w, sh, sm);
        int ot = o >> 4, mm = o & 15, kk = c >> 5, q = (c & 31) >> 3, j = c & 7;
        int within = (q * 16 + mm) * 8 + j;
        Wf[65536 + ((kk) * 8 + ot) * 512 + within] = (short)sh;
        Wf[65536 + ((8 + kk) * 8 + ot) * 512 + within] = (short)sm;
      }
    }
    return;
  }

  if (bid < 438) {
    // ================= c1/c2 split =================
    int idx2 = (bid - 406) * 256 + t;              // 0..8191
#pragma unroll
    for (int e = 0; e < 4; ++e) {
      int i = idx2 * 4 + e;                        // 0..32767
      int c = i & 127, o = (i >> 7) & 127, l = i >> 14;
      float w = (l ? c2w : c1w)[o * 128 + c];
      unsigned sh, sm;
      split2rn(w, sh, sm);
      int ot = o >> 4, mm = o & 15, kk = c >> 5, q = (c & 31) >> 3, j = c & 7;
      int within = (q * 16 + mm) * 8 + j;
      Wf[131072 + (((l * 2 + 0) * 4 + kk) * 8 + ot) * 512 + within] = (short)sh;
      Wf[131072 + (((l * 2 + 1) * 4 + kk) * 8 + ot) * 512 + within] = (short)sm;
    }
    return;
  }

  // ================= prep constants =================
  if (t < 128) {
    float inv = 1.0f / sqrtf(1.0f + 1e-5f);
    float a1 = m1g[t] * inv;
    prep[t] = a1;
    float a2 = m2g[t] * inv;  prep[256 + t] = a2;  prep[384 + t] = fmaf(m2b[t], a2, m2be[t]);
    float a3 = m3g[t] * inv;  prep[512 + t] = a3;  prep[640 + t] = fmaf(m3b[t], a3, m3be[t]);
    float ac1 = c1g[t] * inv; prep[768 + t] = ac1; prep[896 + t] = fmaf(c1b[t], ac1, c1be[t]);
    float ac2 = c2g[t] * inv; prep[1024 + t] = ac2; prep[1152 + t] = fmaf(c2b[t], ac2, c2be[t]);
    prep[1280 + 4 * t + 0] = m1w[t * 259 + 0] * a1;
    prep[1280 + 4 * t + 1] = m1w[t * 259 + 1] * a1;
    prep[1280 + 4 * t + 2] = m1w[t * 259 + 2] * a1;
    prep[1280 + 4 * t + 3] = m1be[t];
  }
}

// ---------------- MFMA GEMM over one 128(c) x nst_h*16(s) fragment buffer ----------
__device__ __forceinline__ void mfma_layer(const short* __restrict__ Wf,
                                           const short* hfrag, int l,
                                           int wave, int lane, int nst_h,
                                           f32x4 acc[2][4])
{
#pragma unroll 1
  for (int kk = 0; kk < 4; ++kk) {
    bf16x8 a[2][2];
#pragma unroll
    for (int oi = 0; oi < 2; ++oi)
#pragma unroll
      for (int sp = 0; sp < 2; ++sp)
        a[oi][sp] = *(const bf16x8*)(Wf + (((l * 2 + sp) * 4 + kk) * 8 + (wave * 2 + oi)) * 512 + lane * 8);
    for (int st = 0; st < nst_h; ++st) {
      const short* hb = hfrag + kk * 2048 + st * 512 + lane * 8;
      bf16x8 b0 = *(const bf16x8*)(hb);           // hi
      bf16x8 b1 = *(const bf16x8*)(hb + 8192);    // mid
#pragma unroll
      for (int oi = 0; oi < 2; ++oi) {
        f32x4 c = acc[oi][st];
        c = __builtin_amdgcn_mfma_f32_16x16x32_bf16(a[oi][1], b0, c, 0, 0, 0);
        c = __builtin_amdgcn_mfma_f32_16x16x32_bf16(a[oi][0], b1, c, 0, 0, 0);
        c = __builtin_amdgcn_mfma_f32_16x16x32_bf16(a[oi][0], b0, c, 0, 0, 0);
        acc[oi][st] = c;
      }
    }
  }
}

// ---------------- fused SA: 4 balls per block, tiles packed over passes ----------
__global__ __launch_bounds__(256, 3) void sa_kernel(
    const float* __restrict__ xc, const float* __restrict__ nxyz,
    const int* __restrict__ bidx, const int* __restrict__ counts,
    const float* __restrict__ W1f, const float* __restrict__ prep,
    const short* __restrict__ Wf, float* __restrict__ feat_out)
{
  __shared__ __align__(16) short hfrag[16384];   // 32KB
  __shared__ float pcs[512];
  __shared__ float sm[32 * 128];                 // 16KB per-tile o-max
  __shared__ float ccen[12];
  __shared__ int scnt[4];
  int gb = blockIdx.x, bk = gb >> 5, pb = (gb & 31) << 2;
  int t = threadIdx.x;
  int wave = t >> 6, lane = t & 63;
  int quad = lane >> 4, nl = lane & 15;

  pcs[t] = prep[1280 + t];
  pcs[256 + t] = prep[1536 + t];
  if (t < 4) scnt[t] = counts[bk * 128 + pb + t];
  if (t < 12) {
    int bb = t / 3, c = t % 3;
    ccen[t] = nxyz[(bk * 128 + pb + bb) * 3 + c];
  }
  __syncthreads();
  int n0 = (scnt[0] + 15) >> 4, n1 = (scnt[1] + 15) >> 4;
  int n2 = (scnt[2] + 15) >> 4, n3 = (scnt[3] + 15) >> 4;
  int pf1 = n0, pf2 = n0 + n1, pf3 = n0 + n1 + n2, T = n0 + n1 + n2 + n3;

  for (int q0 = 0; q0 < T; q0 += 4) {
    int nst_h = T - q0;
    if (nst_h > 4) nst_h = 4;
    // ---- h1 build ----
    {
      int cg = wave;
      int st = lane >> 4, sl = lane & 15;
      if (st < nst_h) {
        int q = q0 + st;
        int bq = (q >= pf1) + (q >= pf2) + (q >= pf3);
        int tstart = (bq == 0) ? 0 : (bq == 1) ? pf1 : (bq == 2) ? pf2 : pf3;
        int tslot = q - tstart;
        int m = bidx[((size_t)(bk * 128 + pb + bq)) * 128 + tslot * 16 + sl];
        float cen0 = ccen[bq * 3 + 0], cen1 = ccen[bq * 3 + 1], cen2 = ccen[bq * 3 + 2];
        float g0 = (xc[(bk * 3 + 0) * 1024 + m] - cen0) * (1.0f / 0.15f);
        float g1 = (xc[(bk * 3 + 1) * 1024 + m] - cen1) * (1.0f / 0.15f);
        float g2 = (xc[(bk * 3 + 2) * 1024 + m] - cen2) * (1.0f / 0.15f);
        const float4* wrow = (const float4*)(W1f + ((size_t)(bk * 1024 + m)) * 128 + cg * 32);
        const float4* pcp = (const float4*)pcs + cg * 32;
#pragma unroll
        for (int g = 0; g < 4; ++g) {
          float4 wva = wrow[g * 2], wvb = wrow[g * 2 + 1];
          float wv[8] = {wva.x, wva.y, wva.z, wva.w, wvb.x, wvb.y, wvb.z, wvb.w};
          unsigned sh[8], smv[8];
#pragma unroll
          for (int e = 0; e < 8; ++e) {
            float4 pc = pcp[g * 8 + e];
            float hv = fmaxf(wv[e] + pc.x * g0 + pc.y * g1 + pc.z * g2 + pc.w, 0.f);
            split2rn(hv, sh[e], smv[e]);
          }
          int base = (cg * 4 + st) * 512 + (g * 16 + sl) * 8;
          v4i ph = {(int)(sh[0] | (sh[1] << 16)), (int)(sh[2] | (sh[3] << 16)),
                    (int)(sh[4] | (sh[5] << 16)), (int)(sh[6] | (sh[7] << 16))};
          *(v4i*)&hfrag[base] = ph;
          v4i pm = {(int)(smv[0] | (smv[1] << 16)), (int)(smv[2] | (smv[3] << 16)),
                    (int)(smv[4] | (smv[5] << 16)), (int)(smv[6] | (smv[7] << 16))};
          *(v4i*)&hfrag[base + 8192] = pm;
        }
      }
    }
    __syncthreads();

    // ---- layer 2 ----
    f32x4 acc[2][4];
#pragma unroll
    for (int oi = 0; oi < 2; ++oi)
#pragma unroll
      for (int st = 0; st < 4; ++st) acc[oi][st] = (f32x4){0.f, 0.f, 0.f, 0.f};
    mfma_layer(Wf, hfrag, 0, wave, lane, nst_h, acc);
    __syncthreads();

    // ---- h2 epilogue ----
#pragma unroll
    for (int oi = 0; oi < 2; ++oi) {
      int o0 = (wave * 2 + oi) * 16 + quad * 4;
      float4 al = *(const float4*)&prep[256 + o0];
      float4 be = *(const float4*)&prep[384 + o0];
      int kk2 = o0 >> 5, g2 = (o0 & 31) >> 3, j0 = o0 & 7;
      for (int st = 0; st < nst_h; ++st) {
        f32x4 cc = acc[oi][st];
        float v0 = fmaxf(fmaf(cc[0], al.x, be.x), 0.f);
        float v1 = fmaxf(fmaf(cc[1], al.y, be.y), 0.f);
        float v2 = fmaxf(fmaf(cc[2], al.z, be.z), 0.f);
        float v3 = fmaxf(fmaf(cc[3], al.w, be.w), 0.f);
        unsigned h0, m0_, h1, m1_, h2, m2_, h3, m3_;
        split2rn(v0, h0, m0_); split2rn(v1, h1, m1_);
        split2rn(v2, h2, m2_); split2rn(v3, h3, m3_);
        int base = (kk2 * 4 + st) * 512 + (g2 * 16 + nl) * 8 + j0;
        v2i w0 = {(int)(h0 | (h1 << 16)), (int)(h2 | (h3 << 16))};
        *(v2i*)&hfrag[base] = w0;
        v2i w1 = {(int)(m0_ | (m1_ << 16)), (int)(m2_ | (m3_ << 16))};
        *(v2i*)&hfrag[base + 8192] = w1;
      }
    }
    __syncthreads();

    // ---- layer 3 ----
#pragma unroll
    for (int oi = 0; oi < 2; ++oi)
#pragma unroll
      for (int st = 0; st < 4; ++st) acc[oi][st] = (f32x4){0.f, 0.f, 0.f, 0.f};
    mfma_layer(Wf, hfrag, 1, wave, lane, nst_h, acc);

    // ---- layer-3 epilogue: BN+ReLU, quad-reduce max per tile ----
#pragma unroll
    for (int oi = 0; oi < 2; ++oi) {
      int o0 = (wave * 2 + oi) * 16 + quad * 4;
      float4 al = *(const float4*)&prep[512 + o0];
      float4 be = *(const float4*)&prep[640 + o0];
      for (int st = 0; st < nst_h; ++st) {
        f32x4 cc = acc[oi][st];
        float v[4];
        v[0] = fmaxf(fmaf(cc[0], al.x, be.x), 0.f);
        v[1] = fmaxf(fmaf(cc[1], al.y, be.y), 0.f);
        v[2] = fmaxf(fmaf(cc[2], al.z, be.z), 0.f);
        v[3] = fmaxf(fmaf(cc[3], al.w, be.w), 0.f);
#pragma unroll
        for (int r = 0; r < 4; ++r) {
          float x = v[r];
          x = fmaxf(x, __shfl_xor(x, 1));
          x = fmaxf(x, __shfl_xor(x, 2));
          x = fmaxf(x, __shfl_xor(x, 4));
          x = fmaxf(x, __shfl_xor(x, 8));
          if (nl == 0) sm[(q0 + st) * 128 + o0 + r] = x;
        }
      }
    }
    __syncthreads();
  }

  // ---- final: merge tiles per ball, write feat ----
#pragma unroll
  for (int e = t; e < 512; e += 256) {
    int bb = e >> 7, o = e & 127;
    int qs = (bb == 0) ? 0 : (bb == 1) ? pf1 : (bb == 2) ? pf2 : pf3;
    int nq = (bb == 0) ? n0 : (bb == 1) ? n1 : (bb == 2) ? n2 : n3;
    float v = sm[qs * 128 + o];
    for (int q = 1; q < nq; ++q) v = fmaxf(v, sm[(qs + q) * 128 + o]);
    feat_out[(((size_t)bk) << 14) + (o << 7) + pb + bb] = v;
  }
}

// ---------------- head: c1 -> c2 (split2 MFMA) -> op -> scores; 2 blocks/bk ------
__global__ __launch_bounds__(256) void head_kernel(const float* __restrict__ featg,
    const float* __restrict__ prep, const short* __restrict__ Wf,
    const float* __restrict__ nxyz, const float* __restrict__ opw,
    const float* __restrict__ opb, float* __restrict__ scores)
{
  __shared__ __align__(16) short hfrag[16384];   // 32KB frags (128c x 64p)
  __shared__ float hplain[128 * 65];             // stride 65 vs conflicts
  int bk = blockIdx.x >> 1, p0 = (blockIdx.x & 1) << 6;
  int t = threadIdx.x;
  int wave = t >> 6, lane = t & 63;
  int quad = lane >> 4, nl = lane & 15;
  const short* WC = Wf + 131072;

  // ---- stage feat[c][p0..p0+63] into split2 B-frags ----
  {
    int cg = wave;
    int st = lane >> 4, sl = lane & 15;
    const float* fb = featg + (bk << 14) + p0 + lane;
#pragma unroll
    for (int g = 0; g < 4; ++g) {
      float v[8];
#pragma unroll
      for (int e = 0; e < 8; ++e)
        v[e] = fb[(cg * 32 + g * 8 + e) << 7];
      unsigned sh[8], sm[8];
#pragma unroll
      for (int e = 0; e < 8; ++e) split2rn(v[e], sh[e], sm[e]);
      int base = (cg * 4 + st) * 512 + (g * 16 + sl) * 8;
      v4i ph = {(int)(sh[0] | (sh[1] << 16)), (int)(sh[2] | (sh[3] << 16)),
                (int)(sh[4] | (sh[5] << 16)), (int)(sh[6] | (sh[7] << 16))};
      *(v4i*)&hfrag[base] = ph;
      v4i pm = {(int)(sm[0] | (sm[1] << 16)), (int)(sm[2] | (sm[3] << 16)),
                (int)(sm[4] | (sm[5] << 16)), (int)(sm[6] | (sm[7] << 16))};
      *(v4i*)&hfrag[base + 8192] = pm;
    }
  }
  __syncthreads();

  // ---- c1 ----
  f32x4 acc[2][4];
#pragma unroll
  for (int oi = 0; oi < 2; ++oi)
#pragma unroll
    for (int st = 0; st < 4; ++st) acc[oi][st] = (f32x4){0.f, 0.f, 0.f, 0.f};
  mfma_layer(WC, hfrag, 0, wave, lane, 4, acc);
  __syncthreads();

  // ---- c1 epilogue: BN+ReLU, write back frags ----
#pragma unroll
  for (int oi = 0; oi < 2; ++oi) {
    int o0 = (wave * 2 + oi) * 16 + quad * 4;
    float4 al = *(const float4*)&prep[768 + o0];
    float4 be = *(const float4*)&prep[896 + o0];
    int kk2 = o0 >> 5, g2 = (o0 & 31) >> 3, j0 = o0 & 7;
#pragma unroll
    for (int st = 0; st < 4; ++st) {
      f32x4 cc = acc[oi][st];
      float v0 = fmaxf(fmaf(cc[0], al.x, be.x), 0.f);
      float v1 = fmaxf(fmaf(cc[1], al.y, be.y), 0.f);
      float v2 = fmaxf(fmaf(cc[2], al.z, be.z), 0.f);
      float v3 = fmaxf(fmaf(cc[3], al.w, be.w), 0.f);
      unsigned h0, m0_, h1, m1_, h2, m2_, h3, m3_;
      split2rn(v0, h0, m0_); split2rn(v1, h1, m1_);
      split2rn(v2, h2, m2_); split2rn(v3, h3, m3_);
      int base = (kk2 * 4 + st) * 512 + (g2 * 16 + nl) * 8 + j0;
      v2i w0 = {(int)(h0 | (h1 << 16)), (int)(h2 | (h3 << 16))};
      *(v2i*)&hfrag[base] = w0;
      v2i w1 = {(int)(m0_ | (m1_ << 16)), (int)(m2_ | (m3_ << 16))};
      *(v2i*)&hfrag[base + 8192] = w1;
    }
  }
  __syncthreads();

  // ---- c2 ----
#pragma unroll
  for (int oi = 0; oi < 2; ++oi)
#pragma unroll
    for (int st = 0; st < 4; ++st) acc[oi][st] = (f32x4){0.f, 0.f, 0.f, 0.f};
  mfma_layer(WC, hfrag, 1, wave, lane, 4, acc);

  // ---- c2 epilogue: BN+ReLU -> hplain[c][p] ----
#pragma unroll
  for (int oi = 0; oi < 2; ++oi) {
    int o0 = (wave * 2 + oi) * 16 + quad * 4;
    float4 al = *(const float4*)&prep[1024 + o0];
    float4 be = *(const float4*)&prep[1152 + o0];
#pragma unroll
    for (int st = 0; st < 4; ++st) {
      f32x4 cc = acc[oi][st];
      int p = st * 16 + nl;
      hplain[(o0 + 0) * 65 + p] = fmaxf(fmaf(cc[0], al.x, be.x), 0.f);
      hplain[(o0 + 1) * 65 + p] = fmaxf(fmaf(cc[1], al.y, be.y), 0.f);
      hplain[(o0 + 2) * 65 + p] = fmaxf(fmaf(cc[2], al.z, be.z), 0.f);
      hplain[(o0 + 3) * 65 + p] = fmaxf(fmaf(cc[3], al.w, be.w), 0.f);
    }
  }
  __syncthreads();

  // ---- op head + scores ----
  if (t < 64) {
    int p = t, k = bk % 19;
    float res[5];
#pragma unroll
    for (int j = 0; j < 5; ++j) {
      const float* wr = opw + ((size_t)(k * 5 + j)) * 128;
      float a = opb[k * 5 + j];
      for (int c = 0; c < 128; ++c) a = fmaf(wr[c], hplain[c * 65 + p], a);
      res[j] = a;
    }
    int pg = p0 + p;
    float a0 = nxyz[(bk * 128 + pg) * 3 + 0];
    float a1 = nxyz[(bk * 128 + pg) * 3 + 1];
    float a2 = nxyz[(bk * 128 + pg) * 3 + 2];
    float* sc = scores + ((size_t)(bk * 128 + pg)) * 5;
    sc[0] = res[0];
    sc[1] = res[1];
    sc[2] = a0 + res[2];
    sc[3] = a1 + res[3];
    sc[4] = a2 + res[4];
  }
}

extern "C" void kernel_launch(void* const* d_in, const int* in_sizes, int n_in,
                              void* d_out, int out_size, void* d_ws, size_t ws_size,
                              hipStream_t stream) {
  (void)in_sizes; (void)n_in; (void)out_size; (void)ws_size;
  const float* xyz  = (const float*)d_in[0];
  const float* fts  = (const float*)d_in[1];
  const float* m1w  = (const float*)d_in[2];
  const float* m1b  = (const float*)d_in[3];
  const float* m1g  = (const float*)d_in[4];
  const float* m1be = (const float*)d_in[5];
  const float* m2w  = (const float*)d_in[6];
  const float* m2b  = (const float*)d_in[7];
  const float* m2g  = (const float*)d_in[8];
  const float* m2be = (const float*)d_in[9];
  const float* m3w  = (const float*)d_in[10];
  const float* m3b  = (const float*)d_in[11];
  const float* m3g  = (const float*)d_in[12];
  const float* m3be = (const float*)d_in[13];
  const float* c1w  = (const float*)d_in[14];
  const float* c1b  = (const float*)d_in[15];
  const float* c1g  = (const float*)d_in[16];
  const float* c1be = (const float*)d_in[17];
  const float* c2w  = (const float*)d_in[18];
  const float* c2b  = (const float*)d_in[19];
  const float* c2g  = (const float*)d_in[20];
  const float* c2be = (const float*)d_in[21];
  const float* opw  = (const float*)d_in[22];
  const float* opb  = (const float*)d_in[23];

  float* out = (float*)d_out;
  char* ws = (char*)d_ws;
  float* xc   = (float*)(ws + OFF_XC);
  float* nxyz = (float*)(ws + OFF_NXYZ);
  int*   bidx = (int*)(ws + OFF_BIDX);
  float* W1f  = (float*)(ws + OFF_W1F);
  float* prep = (float*)(ws + OFF_PREP);
  short* Wf   = (short*)(ws + OFF_WF);
  int*   cnt  = (int*)(ws + OFF_CNT);

  hipLaunchKernelGGL(front_kernel, dim3(439), dim3(256), 0, stream,
                     xyz, fts, m1w, m1b, m1g, m1be, m2w, m2b, m2g, m2be,
                     m3w, m3b, m3g, m3be, c1w, c1b, c1g, c1be,
                     c2w, c2b, c2g, c2be,
                     xc, nxyz, out + OUT_AGG, bidx, cnt, W1f, Wf, prep);
  hipLaunchKernelGGL(sa_kernel, dim3(NBK * 32), dim3(256), 0, stream,
                     xc, nxyz, bidx, cnt, W1f, prep, Wf, out + OUT_FEAT);
  hipLaunchKernelGGL(head_kernel, dim3(NBK * 2), dim3(256), 0, stream,
                     out + OUT_FEAT, prep, Wf, nxyz, opw, opb, out);
}

// Round 9
// 302.435 us; speedup vs baseline: 1.2496x; 1.1011x over previous
//
#include <hip/hip_runtime.h>
#include <math.h>

// ---------------- problem constants ----------------
// B=2, K=19 -> BK=38 batches; M=1024 points; C=256 feat ch; NPOINT=NSAMPLE=128
#define NBK   38

// ---------------- workspace layout (bytes) ----------------
#define OFF_XC    0u          // [38][3][1024] f32        = 466944
#define OFF_NXYZ  466944u     // [38][128][3]  f32        = 58368
#define OFF_BIDX  525312u     // [38][128][128] i32       = 2490368
#define OFF_W1F   3015680u    // [38][1024][128] f32      = 19922944
#define OFF_PREP  22938624u   // 4096 f32
#define OFF_WF    22955008u   // 196608 shorts: w2/w3 (0), unused (65536), c1/c2 (131072)
#define OFF_CNT   23348224u   // [38][128] i32 ball counts = 19456

// ---------------- d_out layout (float offsets) ----------------
#define OUT_AGG   24320       // scores at 0: (2,19,128,5)
#define OUT_FEAT  38912       // agg: (2,19,128,3), feat: (2,19,128,128)

typedef short bf16x8 __attribute__((ext_vector_type(8)));   // 8 bf16 = 4 VGPR
typedef float f32x4  __attribute__((ext_vector_type(4)));
typedef int   v4i    __attribute__((ext_vector_type(4)));
typedef int   v2i    __attribute__((ext_vector_type(2)));

// exact IEEE fp32 squared distance, no FMA contraction, ((d0^2+d1^2)+d2^2)
__device__ __forceinline__ float dist2f(float a0, float a1, float a2,
                                        float b0, float b1, float b2) {
#pragma clang fp contract(off)
  float d0 = a0 - b0;
  float d1 = a1 - b1;
  float d2 = a2 - b2;
  return d0 * d0 + d1 * d1 + d2 * d2;
}

// 2-way bf16 split with round-to-nearest-even: v ~= hi + mid, residual <= 2^-18 |v|
__device__ __forceinline__ void split2rn(float v, unsigned& sh, unsigned& sm) {
  unsigned u = __float_as_uint(v);
  unsigned rh = (u + 0x7fffu + ((u >> 16) & 1u)) & 0xffff0000u;
  sh = rh >> 16;
  float r1 = v - __uint_as_float(rh);        // exact in fp32
  unsigned u1 = __float_as_uint(r1);
  unsigned rm = (u1 + 0x7fffu + ((u1 >> 16) & 1u)) & 0xffff0000u;
  sm = rm >> 16;
}

// ---------------- K1 "front" (1024-thread blocks) ----------------
// blocks 0..37: fps+ball (16 waves); 38..341: w1f (256 active threads);
// 342..349: w2/w3 split; 350..357: c1/c2 split; 358: prep constants.
__global__ __launch_bounds__(1024, 4) void front_kernel(
    const float* __restrict__ xyz, const float* __restrict__ feats,
    const float* __restrict__ m1w, const float* __restrict__ m1b,
    const float* __restrict__ m1g, const float* __restrict__ m1be,
    const float* __restrict__ m2w, const float* __restrict__ m2b,
    const float* __restrict__ m2g, const float* __restrict__ m2be,
    const float* __restrict__ m3w, const float* __restrict__ m3b,
    const float* __restrict__ m3g, const float* __restrict__ m3be,
    const float* __restrict__ c1w, const float* __restrict__ c1b,
    const float* __restrict__ c1g, const float* __restrict__ c1be,
    const float* __restrict__ c2w, const float* __restrict__ c2b,
    const float* __restrict__ c2g, const float* __restrict__ c2be,
    float* __restrict__ xc, float* __restrict__ nxyz, float* __restrict__ agg,
    int* __restrict__ bidx, int* __restrict__ counts,
    float* __restrict__ W1f, short* __restrict__ Wf, float* __restrict__ prep)
{
  __shared__ __align__(16) char smem[32768];
  int bid = blockIdx.x, t = threadIdx.x;
  int wave = t >> 6, lane = t & 63;

  if (bid < NBK) {
    // ================= fps (R4-proven shape) + ball =================
    int bk = bid;
    int b = bk / 19, k = bk % 19;
    float* sx0 = (float*)smem;                  // 1024 f32
    float* sx1 = sx0 + 1024;
    float* sx2 = sx1 + 1024;
    float* scen = sx2 + 1024;                   // 384 f32
    float* sd = scen + 384;                     // 16 f32 (per-wave max dist)
    int* si = (int*)(sd + 16);                  // 16 ints (per-wave min idx)
    int* sfar = si + 16;                        // 1 int

    const float* src = xyz + ((size_t)((b * 1024 + t) * 19 + k)) * 3;
    float x0 = src[0], x1 = src[1], x2 = src[2];
    sx0[t] = x0; sx1[t] = x1; sx2[t] = x2;
    xc[(bk * 3 + 0) * 1024 + t] = x0;
    xc[(bk * 3 + 1) * 1024 + t] = x1;
    xc[(bk * 3 + 2) * 1024 + t] = x2;
    if (t == 0) *sfar = 0;
    float dist = 1e10f;
    __syncthreads();

    for (int it = 0; it < 128; ++it) {
      int far = *sfar;
      float c0 = sx0[far], c1 = sx1[far], c2 = sx2[far];
      if (t < 3) scen[it * 3 + t] = (t == 0) ? c0 : ((t == 1) ? c1 : c2);
      float d = dist2f(x0, x1, x2, c0, c1, c2);
      dist = fminf(dist, d);
      // in-wave: f32 butterfly max (6 shfl), then ballot+ctz = exact min index
      float dmax = dist;
#pragma unroll
      for (int off = 1; off <= 32; off <<= 1)
        dmax = fmaxf(dmax, __shfl_xor(dmax, off));
      unsigned long long mk = __ballot(dist == dmax);
      if (lane == 0) {
        sd[wave] = dmax;
        si[wave] = (wave << 6) + __builtin_ctzll(mk);
      }
      __syncthreads();
      if (t < 16) {
        float dw = sd[t]; int iw = si[t];
        // 64-bit key: max dist wins, ties -> smallest index (jnp.argmax first-max)
        unsigned long long key =
            ((unsigned long long)__float_as_uint(dw) << 32) | (unsigned)(1023 - iw);
#pragma unroll
        for (int off = 8; off >= 1; off >>= 1) {
          unsigned hi = (unsigned)(key >> 32), lo = (unsigned)key;
          unsigned h2 = __shfl_xor(hi, off);
          unsigned l2 = __shfl_xor(lo, off);
          unsigned long long ok = ((unsigned long long)h2 << 32) | l2;
          if (ok > key) key = ok;
        }
        if (t == 0) *sfar = 1023 - (int)(key & 0xffffffffu);
      }
      __syncthreads();
    }

    // ---- flush centers to global once ----
    if (t < 384) {
      float v = scen[t];
      nxyz[bk * 384 + t] = v;
      agg[bk * 384 + t]  = v;
    }

    // ---- ball query: 16 waves x 8 balls from LDS ----
    for (int p = wave * 8; p < wave * 8 + 8; ++p) {
      float c0 = scen[p * 3 + 0], c1 = scen[p * 3 + 1], c2 = scen[p * 3 + 2];
      int* outp = bidx + ((size_t)(bk * 128 + p)) * 128;
      int count = 0, first = 0;
      bool got = false;
      for (int ch = 0; ch < 16 && count < 128; ++ch) {
        int m = (ch << 6) + lane;
        float d = dist2f(sx0[m], sx1[m], sx2[m], c0, c1, c2);
        bool flag = d < 0.0225f;                 // strict fp32, RADIUS^2
        unsigned long long mask = __ballot(flag);
        if (!got && mask) { first = (ch << 6) + __builtin_ctzll(mask); got = true; }
        int pos = count + (int)__popcll(mask & ((1ull << lane) - 1ull));
        if (flag && pos < 128) outp[pos] = m;
        count += (int)__popcll(mask);
      }
      for (int j = count + lane; j < 128; j += 64) outp[j] = first;
      if (lane == 0) counts[bk * 128 + p] = count > 128 ? 128 : count;
    }
    return;
  }

  if (bid < 342) {
    // ================= w1f: 256 active threads; idle waves match 8 barriers =====
    short* ffrag = (short*)smem;                  // 32KB
    if (t >= 256) {
      for (int i = 0; i < 8; ++i) __syncthreads();
      return;
    }
    int blk = bid - NBK;
    int bk = blk >> 3, m0 = (blk & 7) << 7;
    int b = bk / 19, k = bk % 19;
    int quad = lane >> 4, nl = lane & 15;
    int mloc = t & 127, chalf = t >> 7;
    int st_w = mloc >> 4, sl_w = mloc & 15;
    const float* fbase = feats + ((size_t)(b * 4864 + k)) * 1024 + m0 + mloc;

    f32x4 acc[2][8];
#pragma unroll
    for (int oi = 0; oi < 2; ++oi)
#pragma unroll
      for (int st = 0; st < 8; ++st) acc[oi][st] = (f32x4){0.f, 0.f, 0.f, 0.f};

    for (int ch = 0; ch < 4; ++ch) {
      int cbase = ch * 64 + chalf * 32;
#pragma unroll
      for (int g = 0; g < 4; ++g) {
        float v[8];
#pragma unroll
        for (int j = 0; j < 8; ++j)
          v[j] = fbase[(size_t)(cbase + g * 8 + j) * 19456];
        unsigned sh[8], sm[8];
#pragma unroll
        for (int j = 0; j < 8; ++j) split2rn(v[j], sh[j], sm[j]);
        int base = chalf * 4096 + st_w * 512 + (g * 16 + sl_w) * 8;
        v4i ph = {(int)(sh[0] | (sh[1] << 16)), (int)(sh[2] | (sh[3] << 16)),
                  (int)(sh[4] | (sh[5] << 16)), (int)(sh[6] | (sh[7] << 16))};
        *(v4i*)&ffrag[base] = ph;
        v4i pm = {(int)(sm[0] | (sm[1] << 16)), (int)(sm[2] | (sm[3] << 16)),
                  (int)(sm[4] | (sm[5] << 16)), (int)(sm[6] | (sm[7] << 16))};
        *(v4i*)&ffrag[base + 8192] = pm;
      }
      __syncthreads();
#pragma unroll
      for (int kkl = 0; kkl < 2; ++kkl) {
        int kk = ch * 2 + kkl;
        bf16x8 a[2][2];
#pragma unroll
        for (int oi = 0; oi < 2; ++oi) {
          int o_row = (wave * 2 + oi) * 16 + nl;
          const float* wsrc = m1w + o_row * 259 + 3 + kk * 32 + quad * 8;
          float wv[8];
#pragma unroll
          for (int j = 0; j < 8; ++j) wv[j] = wsrc[j];
          unsigned sh[8], sm[8];
#pragma unroll
          for (int j = 0; j < 8; ++j) split2rn(wv[j], sh[j], sm[j]);
          short ah[8], am[8];
#pragma unroll
          for (int j = 0; j < 8; ++j) { ah[j] = (short)sh[j]; am[j] = (short)sm[j]; }
          a[oi][0] = (bf16x8){ah[0], ah[1], ah[2], ah[3], ah[4], ah[5], ah[6], ah[7]};
          a[oi][1] = (bf16x8){am[0], am[1], am[2], am[3], am[4], am[5], am[6], am[7]};
        }
#pragma unroll
        for (int st = 0; st < 8; ++st) {
          const short* hb = ffrag + kkl * 4096 + st * 512 + lane * 8;
          bf16x8 b0 = *(const bf16x8*)hb;
          bf16x8 b1 = *(const bf16x8*)(hb + 8192);
#pragma unroll
          for (int oi = 0; oi < 2; ++oi) {
            f32x4 c = acc[oi][st];
            c = __builtin_amdgcn_mfma_f32_16x16x32_bf16(a[oi][1], b0, c, 0, 0, 0);
            c = __builtin_amdgcn_mfma_f32_16x16x32_bf16(a[oi][0], b1, c, 0, 0, 0);
            c = __builtin_amdgcn_mfma_f32_16x16x32_bf16(a[oi][0], b0, c, 0, 0, 0);
            acc[oi][st] = c;
          }
        }
      }
      __syncthreads();
    }
    float inv = 1.0f / sqrtf(1.0f + 1e-5f);
#pragma unroll
    for (int oi = 0; oi < 2; ++oi) {
      int o0 = (wave * 2 + oi) * 16 + quad * 4;
      float4 bb = *(const float4*)&m1b[o0];
      float4 gg = *(const float4*)&m1g[o0];
#pragma unroll
      for (int st = 0; st < 8; ++st) {
        int m_out = m0 + st * 16 + nl;
        f32x4 cc = acc[oi][st];
        float4 r;
        r.x = (cc[0] + bb.x) * (gg.x * inv);
        r.y = (cc[1] + bb.y) * (gg.y * inv);
        r.z = (cc[2] + bb.z) * (gg.z * inv);
        r.w = (cc[3] + bb.w) * (gg.w * inv);
        *(float4*)&W1f[((size_t)(bk * 1024 + m_out)) * 128 + o0] = r;
      }
    }
    return;
  }

  if (bid < 350) {
    // ================= w2/w3 split =================
    int idx = (bid - 342) * 1024 + t;              // 0..8191
#pragma unroll
    for (int e = 0; e < 4; ++e) {
      int i = idx * 4 + e;                         // 0..32767
      int c = i & 127, o = (i >> 7) & 127, l = i >> 14;
      float w = (l ? m3w : m2w)[o * 128 + c];
      unsigned sh, sm;
      split2rn(w, sh, sm);
      int ot = o >> 4, mm = o & 15, kk = c >> 5, q = (c & 31) >> 3, j = c & 7;
      int within = (q * 16 + mm) * 8 + j;
      Wf[(((l * 2 + 0) * 4 + kk) * 8 + ot) * 512 + within] = (short)sh;
      Wf[(((l * 2 + 1) * 4 + kk) * 8 + ot) * 512 + within] = (short)sm;
    }
    return;
  }

  if (bid < 358) {
    // ================= c1/c2 split =================
    int idx2 = (bid - 350) * 1024 + t;             // 0..8191
#pragma unroll
    for (int e = 0; e < 4; ++e) {
      int i = idx2 * 4 + e;                        // 0..32767
      int c = i & 127, o = (i >> 7) & 127, l = i >> 14;
      float w = (l ? c2w : c1w)[o * 128 + c];
      unsigned sh, sm;
      split2rn(w, sh, sm);
      int ot = o >> 4, mm = o & 15, kk = c >> 5, q = (c & 31) >> 3, j = c & 7;
      int within = (q * 16 + mm) * 8 + j;
      Wf[131072 + (((l * 2 + 0) * 4 + kk) * 8 + ot) * 512 + within] = (short)sh;
      Wf[131072 + (((l * 2 + 1) * 4 + kk) * 8 + ot) * 512 + within] = (short)sm;
    }
    return;
  }

  // ================= prep constants =================
  if (t < 128) {
    float inv = 1.0f / sqrtf(1.0f + 1e-5f);
    float a1 = m1g[t] * inv;
    prep[t] = a1;
    float a2 = m2g[t] * inv;  prep[256 + t] = a2;  prep[384 + t] = fmaf(m2b[t], a2, m2be[t]);
    float a3 = m3g[t] * inv;  prep[512 + t] = a3;  prep[640 + t] = fmaf(m3b[t], a3, m3be[t]);
    float ac1 = c1g[t] * inv; prep[768 + t] = ac1; prep[896 + t] = fmaf(c1b[t], ac1, c1be[t]);
    float ac2 = c2g[t] * inv; prep[1024 + t] = ac2; prep[1152 + t] = fmaf(c2b[t], ac2, c2be[t]);
    prep[1280 + 4 * t + 0] = m1w[t * 259 + 0] * a1;
    prep[1280 + 4 * t + 1] = m1w[t * 259 + 1] * a1;
    prep[1280 + 4 * t + 2] = m1w[t * 259 + 2] * a1;
    prep[1280 + 4 * t + 3] = m1be[t];
  }
}

// ---------------- MFMA GEMM over one 128(c) x nst_h*16(s) fragment buffer ----------
__device__ __forceinline__ void mfma_layer(const short* __restrict__ Wf,
                                           const short* hfrag, int l,
                                           int wave, int lane, int nst_h,
                                           f32x4 acc[2][4])
{
#pragma unroll 1
  for (int kk = 0; kk < 4; ++kk) {
    bf16x8 a[2][2];
#pragma unroll
    for (int oi = 0; oi < 2; ++oi)
#pragma unroll
      for (int sp = 0; sp < 2; ++sp)
        a[oi][sp] = *(const bf16x8*)(Wf + (((l * 2 + sp) * 4 + kk) * 8 + (wave * 2 + oi)) * 512 + lane * 8);
    for (int st = 0; st < nst_h; ++st) {
      const short* hb = hfrag + kk * 2048 + st * 512 + lane * 8;
      bf16x8 b0 = *(const bf16x8*)(hb);           // hi
      bf16x8 b1 = *(const bf16x8*)(hb + 8192);    // mid
#pragma unroll
      for (int oi = 0; oi < 2; ++oi) {
        f32x4 c = acc[oi][st];
        c = __builtin_amdgcn_mfma_f32_16x16x32_bf16(a[oi][1], b0, c, 0, 0, 0);
        c = __builtin_amdgcn_mfma_f32_16x16x32_bf16(a[oi][0], b1, c, 0, 0, 0);
        c = __builtin_amdgcn_mfma_f32_16x16x32_bf16(a[oi][0], b0, c, 0, 0, 0);
        acc[oi][st] = c;
      }
    }
  }
}

// ---------------- fused SA: 4 balls per block, tiles packed over passes ----------
__global__ __launch_bounds__(256, 3) void sa_kernel(
    const float* __restrict__ xc, const float* __restrict__ nxyz,
    const int* __restrict__ bidx, const int* __restrict__ counts,
    const float* __restrict__ W1f, const float* __restrict__ prep,
    const short* __restrict__ Wf, float* __restrict__ feat_out)
{
  __shared__ __align__(16) short hfrag[16384];   // 32KB
  __shared__ float pcs[512];
  __shared__ float sm[32 * 128];                 // 16KB per-tile o-max
  __shared__ float ccen[12];
  __shared__ int scnt[4];
  int gb = blockIdx.x, bk = gb >> 5, pb = (gb & 31) << 2;
  int t = threadIdx.x;
  int wave = t >> 6, lane = t & 63;
  int quad = lane >> 4, nl = lane & 15;

  pcs[t] = prep[1280 + t];
  pcs[256 + t] = prep[1536 + t];
  if (t < 4) scnt[t] = counts[bk * 128 + pb + t];
  if (t < 12) {
    int bb = t / 3, c = t % 3;
    ccen[t] = nxyz[(bk * 128 + pb + bb) * 3 + c];
  }
  __syncthreads();
  int n0 = (scnt[0] + 15) >> 4, n1 = (scnt[1] + 15) >> 4;
  int n2 = (scnt[2] + 15) >> 4, n3 = (scnt[3] + 15) >> 4;
  int pf1 = n0, pf2 = n0 + n1, pf3 = n0 + n1 + n2, T = n0 + n1 + n2 + n3;

  for (int q0 = 0; q0 < T; q0 += 4) {
    int nst_h = T - q0;
    if (nst_h > 4) nst_h = 4;
    // ---- h1 build ----
    {
      int cg = wave;
      int st = lane >> 4, sl = lane & 15;
      if (st < nst_h) {
        int q = q0 + st;
        int bq = (q >= pf1) + (q >= pf2) + (q >= pf3);
        int tstart = (bq == 0) ? 0 : (bq == 1) ? pf1 : (bq == 2) ? pf2 : pf3;
        int tslot = q - tstart;
        int m = bidx[((size_t)(bk * 128 + pb + bq)) * 128 + tslot * 16 + sl];
        float cen0 = ccen[bq * 3 + 0], cen1 = ccen[bq * 3 + 1], cen2 = ccen[bq * 3 + 2];
        float g0 = (xc[(bk * 3 + 0) * 1024 + m] - cen0) * (1.0f / 0.15f);
        float g1 = (xc[(bk * 3 + 1) * 1024 + m] - cen1) * (1.0f / 0.15f);
        float g2 = (xc[(bk * 3 + 2) * 1024 + m] - cen2) * (1.0f / 0.15f);
        const float4* wrow = (const float4*)(W1f + ((size_t)(bk * 1024 + m)) * 128 + cg * 32);
        const float4* pcp = (const float4*)pcs + cg * 32;
#pragma unroll
        for (int g = 0; g < 4; ++g) {
          float4 wva = wrow[g * 2], wvb = wrow[g * 2 + 1];
          float wv[8] = {wva.x, wva.y, wva.z, wva.w, wvb.x, wvb.y, wvb.z, wvb.w};
          unsigned sh[8], smv[8];
#pragma unroll
          for (int e = 0; e < 8; ++e) {
            float4 pc = pcp[g * 8 + e];
            float hv = fmaxf(wv[e] + pc.x * g0 + pc.y * g1 + pc.z * g2 + pc.w, 0.f);
            split2rn(hv, sh[e], smv[e]);
          }
          int base = (cg * 4 + st) * 512 + (g * 16 + sl) * 8;
          v4i ph = {(int)(sh[0] | (sh[1] << 16)), (int)(sh[2] | (sh[3] << 16)),
                    (int)(sh[4] | (sh[5] << 16)), (int)(sh[6] | (sh[7] << 16))};
          *(v4i*)&hfrag[base] = ph;
          v4i pm = {(int)(smv[0] | (smv[1] << 16)), (int)(smv[2] | (smv[3] << 16)),
                    (int)(smv[4] | (smv[5] << 16)), (int)(smv[6] | (smv[7] << 16))};
          *(v4i*)&hfrag[base + 8192] = pm;
        }
      }
    }
    __syncthreads();

    // ---- layer 2 ----
    f32x4 acc[2][4];
#pragma unroll
    for (int oi = 0; oi < 2; ++oi)
#pragma unroll
      for (int st = 0; st < 4; ++st) acc[oi][st] = (f32x4){0.f, 0.f, 0.f, 0.f};
    mfma_layer(Wf, hfrag, 0, wave, lane, nst_h, acc);
    __syncthreads();

    // ---- h2 epilogue ----
#pragma unroll
    for (int oi = 0; oi < 2; ++oi) {
      int o0 = (wave * 2 + oi) * 16 + quad * 4;
      float4 al = *(const float4*)&prep[256 + o0];
      float4 be = *(const float4*)&prep[384 + o0];
      int kk2 = o0 >> 5, g2 = (o0 & 31) >> 3, j0 = o0 & 7;
      for (int st = 0; st < nst_h; ++st) {
        f32x4 cc = acc[oi][st];
        float v0 = fmaxf(fmaf(cc[0], al.x, be.x), 0.f);
        float v1 = fmaxf(fmaf(cc[1], al.y, be.y), 0.f);
        float v2 = fmaxf(fmaf(cc[2], al.z, be.z), 0.f);
        float v3 = fmaxf(fmaf(cc[3], al.w, be.w), 0.f);
        unsigned h0, m0_, h1, m1_, h2, m2_, h3, m3_;
        split2rn(v0, h0, m0_); split2rn(v1, h1, m1_);
        split2rn(v2, h2, m2_); split2rn(v3, h3, m3_);
        int base = (kk2 * 4 + st) * 512 + (g2 * 16 + nl) * 8 + j0;
        v2i w0 = {(int)(h0 | (h1 << 16)), (int)(h2 | (h3 << 16))};
        *(v2i*)&hfrag[base] = w0;
        v2i w1 = {(int)(m0_ | (m1_ << 16)), (int)(m2_ | (m3_ << 16))};
        *(v2i*)&hfrag[base + 8192] = w1;
      }
    }
    __syncthreads();

    // ---- layer 3 ----
#pragma unroll
    for (int oi = 0; oi < 2; ++oi)
#pragma unroll
      for (int st = 0; st < 4; ++st) acc[oi][st] = (f32x4){0.f, 0.f, 0.f, 0.f};
    mfma_layer(Wf, hfrag, 1, wave, lane, nst_h, acc);

    // ---- layer-3 epilogue: BN+ReLU, quad-reduce max per tile ----
#pragma unroll
    for (int oi = 0; oi < 2; ++oi) {
      int o0 = (wave * 2 + oi) * 16 + quad * 4;
      float4 al = *(const float4*)&prep[512 + o0];
      float4 be = *(const float4*)&prep[640 + o0];
      for (int st = 0; st < nst_h; ++st) {
        f32x4 cc = acc[oi][st];
        float v[4];
        v[0] = fmaxf(fmaf(cc[0], al.x, be.x), 0.f);
        v[1] = fmaxf(fmaf(cc[1], al.y, be.y), 0.f);
        v[2] = fmaxf(fmaf(cc[2], al.z, be.z), 0.f);
        v[3] = fmaxf(fmaf(cc[3], al.w, be.w), 0.f);
#pragma unroll
        for (int r = 0; r < 4; ++r) {
          float x = v[r];
          x = fmaxf(x, __shfl_xor(x, 1));
          x = fmaxf(x, __shfl_xor(x, 2));
          x = fmaxf(x, __shfl_xor(x, 4));
          x = fmaxf(x, __shfl_xor(x, 8));
          if (nl == 0) sm[(q0 + st) * 128 + o0 + r] = x;
        }
      }
    }
    __syncthreads();
  }

  // ---- final: merge tiles per ball, write feat ----
#pragma unroll
  for (int e = t; e < 512; e += 256) {
    int bb = e >> 7, o = e & 127;
    int qs = (bb == 0) ? 0 : (bb == 1) ? pf1 : (bb == 2) ? pf2 : pf3;
    int nq = (bb == 0) ? n0 : (bb == 1) ? n1 : (bb == 2) ? n2 : n3;
    float v = sm[qs * 128 + o];
    for (int q = 1; q < nq; ++q) v = fmaxf(v, sm[(qs + q) * 128 + o]);
    feat_out[(((size_t)bk) << 14) + (o << 7) + pb + bb] = v;
  }
}

// ---------------- head: c1 -> c2 (split2 MFMA) -> op -> scores; 2 blocks/bk ------
__global__ __launch_bounds__(256) void head_kernel(const float* __restrict__ featg,
    const float* __restrict__ prep, const short* __restrict__ Wf,
    const float* __restrict__ nxyz, const float* __restrict__ opw,
    const float* __restrict__ opb, float* __restrict__ scores)
{
  __shared__ __align__(16) short hfrag[16384];   // 32KB frags (128c x 64p)
  __shared__ float hplain[128 * 65];             // stride 65 vs conflicts
  int bk = blockIdx.x >> 1, p0 = (blockIdx.x & 1) << 6;
  int t = threadIdx.x;
  int wave = t >> 6, lane = t & 63;
  int quad = lane >> 4, nl = lane & 15;
  const short* WC = Wf + 131072;

  // ---- stage feat[c][p0..p0+63] into split2 B-frags ----
  {
    int cg = wave;
    int st = lane >> 4, sl = lane & 15;
    const float* fb = featg + (bk << 14) + p0 + lane;
#pragma unroll
    for (int g = 0; g < 4; ++g) {
      float v[8];
#pragma unroll
      for (int e = 0; e < 8; ++e)
        v[e] = fb[(cg * 32 + g * 8 + e) << 7];
      unsigned sh[8], sm[8];
#pragma unroll
      for (int e = 0; e < 8; ++e) split2rn(v[e], sh[e], sm[e]);
      int base = (cg * 4 + st) * 512 + (g * 16 + sl) * 8;
      v4i ph = {(int)(sh[0] | (sh[1] << 16)), (int)(sh[2] | (sh[3] << 16)),
                (int)(sh[4] | (sh[5] << 16)), (int)(sh[6] | (sh[7] << 16))};
      *(v4i*)&hfrag[base] = ph;
      v4i pm = {(int)(sm[0] | (sm[1] << 16)), (int)(sm[2] | (sm[3] << 16)),
                (int)(sm[4] | (sm[5] << 16)), (int)(sm[6] | (sm[7] << 16))};
      *(v4i*)&hfrag[base + 8192] = pm;
    }
  }
  __syncthreads();

  // ---- c1 ----
  f32x4 acc[2][4];
#pragma unroll
  for (int oi = 0; oi < 2; ++oi)
#pragma unroll
    for (int st = 0; st < 4; ++st) acc[oi][st] = (f32x4){0.f, 0.f, 0.f, 0.f};
  mfma_layer(WC, hfrag, 0, wave, lane, 4, acc);
  __syncthreads();

  // ---- c1 epilogue: BN+ReLU, write back frags ----
#pragma unroll
  for (int oi = 0; oi < 2; ++oi) {
    int o0 = (wave * 2 + oi) * 16 + quad * 4;
    float4 al = *(const float4*)&prep[768 + o0];
    float4 be = *(const float4*)&prep[896 + o0];
    int kk2 = o0 >> 5, g2 = (o0 & 31) >> 3, j0 = o0 & 7;
#pragma unroll
    for (int st = 0; st < 4; ++st) {
      f32x4 cc = acc[oi][st];
      float v0 = fmaxf(fmaf(cc[0], al.x, be.x), 0.f);
      float v1 = fmaxf(fmaf(cc[1], al.y, be.y), 0.f);
      float v2 = fmaxf(fmaf(cc[2], al.z, be.z), 0.f);
      float v3 = fmaxf(fmaf(cc[3], al.w, be.w), 0.f);
      unsigned h0, m0_, h1, m1_, h2, m2_, h3, m3_;
      split2rn(v0, h0, m0_); split2rn(v1, h1, m1_);
      split2rn(v2, h2, m2_); split2rn(v3, h3, m3_);
      int base = (kk2 * 4 + st) * 512 + (g2 * 16 + nl) * 8 + j0;
      v2i w0 = {(int)(h0 | (h1 << 16)), (int)(h2 | (h3 << 16))};
      *(v2i*)&hfrag[base] = w0;
      v2i w1 = {(int)(m0_ | (m1_ << 16)), (int)(m2_ | (m3_ << 16))};
      *(v2i*)&hfrag[base + 8192] = w1;
    }
  }
  __syncthreads();

  // ---- c2 ----
#pragma unroll
  for (int oi = 0; oi < 2; ++oi)
#pragma unroll
    for (int st = 0; st < 4; ++st) acc[oi][st] = (f32x4){0.f, 0.f, 0.f, 0.f};
  mfma_layer(WC, hfrag, 1, wave, lane, 4, acc);

  // ---- c2 epilogue: BN+ReLU -> hplain[c][p] ----
#pragma unroll
  for (int oi = 0; oi < 2; ++oi) {
    int o0 = (wave * 2 + oi) * 16 + quad * 4;
    float4 al = *(const float4*)&prep[1024 + o0];
    float4 be = *(const float4*)&prep[1152 + o0];
#pragma unroll
    for (int st = 0; st < 4; ++st) {
      f32x4 cc = acc[oi][st];
      int p = st * 16 + nl;
      hplain[(o0 + 0) * 65 + p] = fmaxf(fmaf(cc[0], al.x, be.x), 0.f);
      hplain[(o0 + 1) * 65 + p] = fmaxf(fmaf(cc[1], al.y, be.y), 0.f);
      hplain[(o0 + 2) * 65 + p] = fmaxf(fmaf(cc[2], al.z, be.z), 0.f);
      hplain[(o0 + 3) * 65 + p] = fmaxf(fmaf(cc[3], al.w, be.w), 0.f);
    }
  }
  __syncthreads();

  // ---- op head + scores ----
  if (t < 64) {
    int p = t, k = bk % 19;
    float res[5];
#pragma unroll
    for (int j = 0; j < 5; ++j) {
      const float* wr = opw + ((size_t)(k * 5 + j)) * 128;
      float a = opb[k * 5 + j];
      for (int c = 0; c < 128; ++c) a = fmaf(wr[c], hplain[c * 65 + p], a);
      res[j] = a;
    }
    int pg = p0 + p;
    float a0 = nxyz[(bk * 128 + pg) * 3 + 0];
    float a1 = nxyz[(bk * 128 + pg) * 3 + 1];
    float a2 = nxyz[(bk * 128 + pg) * 3 + 2];
    float* sc = scores + ((size_t)(bk * 128 + pg)) * 5;
    sc[0] = res[0];
    sc[1] = res[1];
    sc[2] = a0 + res[2];
    sc[3] = a1 + res[3];
    sc[4] = a2 + res[4];
  }
}

extern "C" void kernel_launch(void* const* d_in, const int* in_sizes, int n_in,
                              void* d_out, int out_size, void* d_ws, size_t ws_size,
                              hipStream_t stream) {
  (void)in_sizes; (void)n_in; (void)out_size; (void)ws_size;
  const float* xyz  = (const float*)d_in[0];
  const float* fts  = (const float*)d_in[1];
  const float* m1w  = (const float*)d_in[2];
  const float* m1b  = (const float*)d_in[3];
  const float* m1g  = (const float*)d_in[4];
  const float* m1be = (const float*)d_in[5];
  const float* m2w  = (const float*)d_in[6];
  const float* m2b  = (const float*)d_in[7];
  const float* m2g  = (const float*)d_in[8];
  const float* m2be = (const float*)d_in[9];
  const float* m3w  = (const float*)d_in[10];
  const float* m3b  = (const float*)d_in[11];
  const float* m3g  = (const float*)d_in[12];
  const float* m3be = (const float*)d_in[13];
  const float* c1w  = (const float*)d_in[14];
  const float* c1b  = (const float*)d_in[15];
  const float* c1g  = (const float*)d_in[16];
  const float* c1be = (const float*)d_in[17];
  const float* c2w  = (const float*)d_in[18];
  const float* c2b  = (const float*)d_in[19];
  const float* c2g  = (const float*)d_in[20];
  const float* c2be = (const float*)d_in[21];
  const float* opw  = (const float*)d_in[22];
  const float* opb  = (const float*)d_in[23];

  float* out = (float*)d_out;
  char* ws = (char*)d_ws;
  float* xc   = (float*)(ws + OFF_XC);
  float* nxyz = (float*)(ws + OFF_NXYZ);
  int*   bidx = (int*)(ws + OFF_BIDX);
  float* W1f  = (float*)(ws + OFF_W1F);
  float* prep = (float*)(ws + OFF_PREP);
  short* Wf   = (short*)(ws + OFF_WF);
  int*   cnt  = (int*)(ws + OFF_CNT);

  hipLaunchKernelGGL(front_kernel, dim3(359), dim3(1024), 0, stream,
                     xyz, fts, m1w, m1b, m1g, m1be, m2w, m2b, m2g, m2be,
                     m3w, m3b, m3g, m3be, c1w, c1b, c1g, c1be,
                     c2w, c2b, c2g, c2be,
                     xc, nxyz, out + OUT_AGG, bidx, cnt, W1f, Wf, prep);
  hipLaunchKernelGGL(sa_kernel, dim3(NBK * 32), dim3(256), 0, stream,
                     xc, nxyz, bidx, cnt, W1f, prep, Wf, out + OUT_FEAT);
  hipLaunchKernelGGL(head_kernel, dim3(NBK * 2), dim3(256), 0, stream,
                     out + OUT_FEAT, prep, Wf, nxyz, opw, opb, out);
}